// Round 10
// baseline (940.577 us; speedup 1.0000x reference)
//
#include <hip/hip_runtime.h>
#include <hip/hip_bf16.h>

// ---------------------------------------------------------------------------
// LinearSystem: chunked parallel scan (128 chunks x 8 steps), bf16 MFMA.
// Round 9b: same as round 9, with p3obs_k LDS pointer arrays replaced by
// runtime address arithmetic (fixes addrspacecast static-init compile error).
// ---------------------------------------------------------------------------

typedef short bfrag __attribute__((ext_vector_type(8)));   // 8 x bf16 bits
typedef float f32x4 __attribute__((ext_vector_type(4)));

__device__ __host__ inline unsigned short f2bf(float f) {
    union { float f; unsigned u; } x; x.f = f;
    unsigned r = x.u + 0x7fffu + ((x.u >> 16) & 1u);   // RNE
    return (unsigned short)(r >> 16);
}
__device__ inline float bf2f(unsigned short h) {
    union { unsigned u; float f; } x; x.u = ((unsigned)h) << 16;
    return x.f;
}

#define MSL 262144L   // 512*512 matrix stride

struct GemmDesc {
    const unsigned short* a0;                // A source (bf16)
    const unsigned short* b;                 // B, bf16, (N,K) row-major (B^T)
    float* c;                                // f32 C out (nullable)
    const unsigned short* cmbeta;            // bf16 beta source (beta==2)
    unsigned short* cm;                      // bf16 mirror out (nullable)
    unsigned short* cmT;                     // bf16 transposed mirror (512x512)
    const unsigned short* a1;                // second A source (k >= ksplit)
    long a0_base, a0_os, a0_is;              // row map: (r>>icl)*os + (r&mask)*is
    long a1_base, a1_os, a1_is;
    long a_zq, a_zr;
    long b_base, b_ldb, b_zq, b_zr;
    long c_base, c_os, c_is, c_zq, c_zr;
    long cm_base, cmb_base, cmT_base;
    long a_shift;                            // prefix rows (copy-only, acc=0)
    int a0_icl, a1_icl, c_icl, zdivl;
    int ksplit, K, beta;                     // beta: 0 none, 2 bf16 cmbeta
    int gxl, gyl, gz_main, gz_ncp;
    // copy role (gz_main <= bz < gz_main+gz_ncp): phase1 t-slice copy
    const unsigned short* cp_src; unsigned short* cp_dst; long cp_nrows;
    // aux power-chain slice (bz >= gz_main+gz_ncp): 512x512 C = xa[z] @ xb^T
    const unsigned short* xa; const unsigned short* xb;
    unsigned short* xcm; unsigned short* xcmT;
};

// 128x128 tile, BK=64, 4 waves (2x2 of 64x64), double-buffered 2-phase.
__global__ __launch_bounds__(256) void gemm_k(GemmDesc d) {
    __shared__ __align__(16) unsigned short As[2][128 * 64];
    __shared__ __align__(16) unsigned short Bs[2][128 * 64];
    const int tid  = threadIdx.x;
    const int lane = tid & 63;
    const int w    = tid >> 6;
    const int wrow = (w >> 1) * 64, wcol = (w & 1) * 64;

    // flattened grid + XCD-chunked bijective swizzle (x fastest)
    const unsigned nx = gridDim.x, ny = gridDim.y;
    const unsigned nwg = nx * ny * gridDim.z;
    unsigned wid = blockIdx.x + nx * (blockIdx.y + ny * blockIdx.z);
    if ((nwg & 7) == 0) wid = (wid & 7) * (nwg >> 3) + (wid >> 3);
    const int bx = wid & (nx - 1);
    const int by = (wid >> d.gxl) & (ny - 1);
    int bz = wid >> (d.gxl + d.gyl);

    if (bz >= d.gz_main) {
        const int aux_z = bz - d.gz_main - d.gz_ncp;
        if (aux_z < 0) {                     // ---- copy role: t-slice copy ----
            const long total = (long)nx * ny * 256;
            const long flatb = wid & (nx * ny - 1);
            for (long i8 = (flatb * 256 + tid) * 8; i8 < d.cp_nrows * 512; i8 += total * 8) {
                const long r = i8 >> 9, s = i8 & 511;
                const long t = r >> 13, q = r & 8191;
                const long off = (q >> 7) * 524288L + (q & 127) * 4096L + t * 512L + s;
                *(bfrag*)(d.cp_dst + off) = *(const bfrag*)(d.cp_src + off);
            }
            return;
        }
        if (by >= 4) return;                 // ---- aux: 512x512 power GEMM ----
        const long za = (long)aux_z * MSL;
        d.a0 = d.xa; d.a0_base = za; d.a0_os = 512; d.a0_is = 0; d.a0_icl = 0;
        d.a1 = nullptr;
        d.b = d.xb; d.b_base = 0; d.b_ldb = 512; d.b_zq = d.b_zr = 0;
        d.K = 512; d.ksplit = 1 << 30; d.beta = 0; d.a_shift = 0;
        d.a_zq = d.a_zr = 0;
        d.c = nullptr; d.cm = d.xcm; d.cm_base = za;
        d.c_os = 512; d.c_is = 0; d.c_icl = 0; d.c_zq = d.c_zr = 0; d.c_base = 0;
        d.cmT = d.xcmT; d.cmT_base = za;
        bz = 0;
    }
    const long zq = (long)bz >> d.zdivl;
    const long zr = (long)bz & ((1L << d.zdivl) - 1);
    const int row0 = by * 128;
    const int col0 = bx * 128;

    const int g_r = tid >> 3;                // staging row within 32-row group
    const int g_k = (tid & 7) * 8;           // 16B k-slot
    const int swz = (g_r & 7) << 3;          // XOR swizzle (8-elem units)
    const long za_ = zq * d.a_zq + zr * d.a_zr;
    const long zb_ = zq * d.b_zq + zr * d.b_zr;

    const long m0a = (1L << d.a0_icl) - 1, m1a = (1L << d.a1_icl) - 1;
    long a0off[4], a1off[4], boff[4];
#pragma unroll
    for (int i = 0; i < 4; ++i) {
        long ar = (long)row0 + i * 32 + g_r - d.a_shift;
        if (ar < 0) ar = 0;
        a0off[i] = d.a0_base + za_ + (ar >> d.a0_icl) * d.a0_os + (ar & m0a) * d.a0_is;
        a1off[i] = d.a1 ? (d.a1_base + za_ + (ar >> d.a1_icl) * d.a1_os + (ar & m1a) * d.a1_is) : 0;
        boff[i]  = d.b_base + zb_ + (long)(col0 + i * 32 + g_r) * d.b_ldb;
    }

    bfrag ar_[4], br_[4];
    auto LOADT = [&](int t) {
        const int k0 = t * 64;
        const bool s1 = (k0 >= d.ksplit);
        const int kb = (s1 ? k0 - d.ksplit : k0) + g_k;
        const unsigned short* sp = s1 ? d.a1 : d.a0;
#pragma unroll
        for (int i = 0; i < 4; ++i)
            ar_[i] = *(const bfrag*)(sp + (s1 ? a1off[i] : a0off[i]) + kb);
#pragma unroll
        for (int i = 0; i < 4; ++i) br_[i] = *(const bfrag*)(d.b + boff[i] + k0 + g_k);
    };
    auto WRT = [&](int buf) {
#pragma unroll
        for (int i = 0; i < 4; ++i) {
            *(bfrag*)&As[buf][(i * 32 + g_r) * 64 + (g_k ^ swz)] = ar_[i];
            *(bfrag*)&Bs[buf][(i * 32 + g_r) * 64 + (g_k ^ swz)] = br_[i];
        }
    };

    f32x4 acc[4][4] = {};
    const int nt = d.K / 64;

    LOADT(0); WRT(0); __syncthreads();
    int cur = 0;
    for (int t = 0; t < nt; ++t) {
        if (t + 1 < nt) LOADT(t + 1);        // issue next-tile loads early
#pragma unroll
        for (int ks = 0; ks < 2; ++ks) {
            const int kk = ks * 32 + (lane >> 4) * 8;
            bfrag af[4], bf_[4];
#pragma unroll
            for (int mt = 0; mt < 4; ++mt) {
                const int r = wrow + mt * 16 + (lane & 15);
                af[mt] = *(const bfrag*)&As[cur][r * 64 + (kk ^ ((r & 7) << 3))];
            }
#pragma unroll
            for (int nn = 0; nn < 4; ++nn) {
                const int r = wcol + nn * 16 + (lane & 15);
                bf_[nn] = *(const bfrag*)&Bs[cur][r * 64 + (kk ^ ((r & 7) << 3))];
            }
#pragma unroll
            for (int mt = 0; mt < 4; ++mt)
#pragma unroll
                for (int nn = 0; nn < 4; ++nn)
                    acc[mt][nn] = __builtin_amdgcn_mfma_f32_16x16x32_bf16(
                        af[mt], bf_[nn], acc[mt][nn], 0, 0, 0);
        }
        if (t + 1 < nt) WRT(cur ^ 1);        // write-late (hidden under compute)
        __syncthreads();                     // ONE barrier per K-step
        cur ^= 1;
    }

    // ---- epilogue ----
    const long zc = zq * d.c_zq + zr * d.c_zr;
    const long mc = (1L << d.c_icl) - 1;
#pragma unroll
    for (int mt = 0; mt < 4; ++mt) {
        const int rb = row0 + wrow + mt * 16 + ((lane >> 4) << 2);
#pragma unroll
        for (int nn = 0; nn < 4; ++nn) {
            const int cc = col0 + wcol + nn * 16 + (lane & 15);
#pragma unroll
            for (int j = 0; j < 4; ++j) {
                const long r = rb + j;
                const long off = zc + (r >> d.c_icl) * d.c_os + (r & mc) * d.c_is + cc;
                float v = (r < d.a_shift) ? 0.0f : acc[mt][nn][j];
                if (d.beta == 2) v += bf2f(d.cmbeta[d.cmb_base + off]);
                if (d.c)  d.c[d.c_base + off] = v;
                if (d.cm) d.cm[d.cm_base + off] = f2bf(v);
                if (d.cmT) d.cmT[d.cmT_base + zc + (long)cc * 512 + r] = f2bf(v);
            }
        }
    }
}

// ---------------------------------------------------------------------------
// Fused phase3 + obs. Grid (8, 64, 1): x = k (XCD-aligned), y = 128-row tile.
// 512 threads. GEMM1 double-buffered (Bs1 2x64K + As1 2x16K = 160K LDS),
// then region reused as Sb[128][512] + Ts[256][64]. LDS addressed via offset
// arithmetic (no pointer arrays -> no addrspacecast static init).
// ---------------------------------------------------------------------------
__global__ __launch_bounds__(512) void p3obs_k(
        const unsigned short* __restrict__ carry, const unsigned short* __restrict__ Gm,
        const unsigned short* __restrict__ Smir, const unsigned short* __restrict__ BopO,
        const float* __restrict__ Vn, float* __restrict__ states, float* __restrict__ obs) {
    __shared__ __align__(16) unsigned char lds[163840];
#define BS1(buf) ((unsigned short*)(lds + (buf) * 65536))
#define AS1(buf) ((unsigned short*)(lds + 131072 + (buf) * 16384))
    unsigned short* Sb = (unsigned short*)lds;             // [128][512] post-GEMM1
    unsigned short* Ts = (unsigned short*)(lds + 131072);  // [256][64]
    unsigned short* A2 = (unsigned short*)lds;             // [128][64] (kt>=8, over Sb)

    const int tid  = threadIdx.x;
    const int lane = tid & 63;
    const int w    = tid >> 6;               // 0..7
    const int wm   = w >> 2, wn = w & 3;     // 2 x 4 wave grid
    const int k    = blockIdx.x;             // 0..7  (one G[k] per XCD)
    const int by   = blockIdx.y;             // 0..63
    const unsigned short* G = Gm + (long)k * MSL;

    const int srow = tid >> 3;               // 0..63
    const int skk  = (tid & 7) * 8;
    const int sw   = (srow & 7) << 3;

    bfrag areg[2], breg[8];
    auto LOADT = [&](int kt) {
#pragma unroll
        for (int i = 0; i < 2; ++i) {
            const int row = srow + i * 64;
            const long rg = (long)by * 128 + row;
            areg[i] = *(const bfrag*)(carry + (rg >> 6) * 32768 + (rg & 63) * 512 + kt * 64 + skk);
        }
#pragma unroll
        for (int i = 0; i < 8; ++i)
            breg[i] = *(const bfrag*)(G + (long)(srow + i * 64) * 512 + kt * 64 + skk);
    };
    auto WRT = [&](int buf) {
        unsigned short* as = AS1(buf);
        unsigned short* bs = BS1(buf);
#pragma unroll
        for (int i = 0; i < 2; ++i)
            *(bfrag*)&as[(srow + i * 64) * 64 + (skk ^ sw)] = areg[i];
#pragma unroll
        for (int i = 0; i < 8; ++i)
            *(bfrag*)&bs[(srow + i * 64) * 64 + (skk ^ sw)] = breg[i];
    };

    // ---------- GEMM1: s = carry @ G^T (pipelined) ----------
    f32x4 acc[4][8] = {};
    LOADT(0); WRT(0); __syncthreads();
    int cur = 0;
    for (int kt = 0; kt < 8; ++kt) {
        if (kt < 7) LOADT(kt + 1);
        const unsigned short* as = AS1(cur);
        const unsigned short* bs = BS1(cur);
#pragma unroll
        for (int ks = 0; ks < 2; ++ks) {
            const int kk = ks * 32 + (lane >> 4) * 8;
            bfrag af[4], bf_[8];
#pragma unroll
            for (int mt = 0; mt < 4; ++mt) {
                const int r = wm * 64 + mt * 16 + (lane & 15);
                af[mt] = *(const bfrag*)&as[r * 64 + (kk ^ ((r & 7) << 3))];
            }
#pragma unroll
            for (int nt = 0; nt < 8; ++nt) {
                const int n = wn * 128 + nt * 16 + (lane & 15);
                bf_[nt] = *(const bfrag*)&bs[n * 64 + (kk ^ ((n & 7) << 3))];
            }
#pragma unroll
            for (int mt = 0; mt < 4; ++mt)
#pragma unroll
                for (int nt = 0; nt < 8; ++nt)
                    acc[mt][nt] = __builtin_amdgcn_mfma_f32_16x16x32_bf16(
                        af[mt], bf_[nt], acc[mt][nt], 0, 0, 0);
        }
        if (kt < 7) WRT(cur ^ 1);
        __syncthreads();
        cur ^= 1;
    }

    // ---------- epilogue 1: +local, write states, build Sb ----------
#pragma unroll
    for (int mt = 0; mt < 4; ++mt) {
#pragma unroll
        for (int nt = 0; nt < 8; ++nt) {
#pragma unroll
            for (int j = 0; j < 4; ++j) {
                const int lr = wm * 64 + mt * 16 + ((lane >> 4) << 2) + j;
                const int cc = wn * 128 + nt * 16 + (lane & 15);
                const long rg = (long)by * 128 + lr;
                const long b = rg & 63;
                const long t = (rg >> 6) * 8 + k;
                float v = acc[mt][nt][j] + bf2f(Smir[b * 524288L + t * 512 + cc]);
                states[b * 524288L + t * 512 + cc] = v;
                Sb[lr * 512 + (cc ^ ((lr & 7) << 3))] = f2bf(v);
            }
        }
    }

    // ---------- GEMM2: obs = [Sb | cvt(Vn)] @ BopO^T ----------
    f32x4 acc2[4][4] = {};
    for (int kt = 0; kt < 12; ++kt) {
        __syncthreads();
#pragma unroll
        for (int i = 0; i < 4; ++i) {        // Ts: BopO rows 0..255
            const int fi = tid + i * 512;
            const int row = fi >> 3, kk = (fi & 7) * 8;
            bfrag v = *(const bfrag*)(BopO + (long)row * 768 + kt * 64 + kk);
            *(bfrag*)&Ts[row * 64 + (kk ^ ((row & 7) << 3))] = v;
        }
        if (kt >= 8) {
#pragma unroll
            for (int i = 0; i < 2; ++i) {    // A2: Vn f32 -> bf16
                const int fi = tid + i * 512;
                const int row = fi >> 3, kk = (fi & 7) * 8;
                const long rg = (long)by * 128 + row;
                const long b = rg & 63;
                const long t = (rg >> 6) * 8 + k;
                const float* p = Vn + b * 262144L + t * 256 + (kt - 8) * 64 + kk;
                f32x4 x0 = *(const f32x4*)p, x1 = *(const f32x4*)(p + 4);
                union { bfrag v; unsigned short h[8]; } u;
#pragma unroll
                for (int q = 0; q < 4; ++q) { u.h[q] = f2bf(x0[q]); u.h[4 + q] = f2bf(x1[q]); }
                *(bfrag*)&A2[row * 64 + (kk ^ ((row & 7) << 3))] = u.v;
            }
        }
        __syncthreads();
#pragma unroll
        for (int ks = 0; ks < 2; ++ks) {
            const int kk = ks * 32 + (lane >> 4) * 8;
            bfrag af[4], bf_[4];
#pragma unroll
            for (int mt = 0; mt < 4; ++mt) {
                const int r = wm * 64 + mt * 16 + (lane & 15);
                af[mt] = (kt < 8)
                    ? *(const bfrag*)&Sb[r * 512 + ((kt * 64 + kk) ^ ((r & 7) << 3))]
                    : *(const bfrag*)&A2[r * 64 + (kk ^ ((r & 7) << 3))];
            }
#pragma unroll
            for (int nt = 0; nt < 4; ++nt) {
                const int n = wn * 64 + nt * 16 + (lane & 15);
                bf_[nt] = *(const bfrag*)&Ts[n * 64 + (kk ^ ((n & 7) << 3))];
            }
#pragma unroll
            for (int mt = 0; mt < 4; ++mt)
#pragma unroll
                for (int nt = 0; nt < 4; ++nt)
                    acc2[mt][nt] = __builtin_amdgcn_mfma_f32_16x16x32_bf16(
                        af[mt], bf_[nt], acc2[mt][nt], 0, 0, 0);
        }
    }
#pragma unroll
    for (int mt = 0; mt < 4; ++mt) {
#pragma unroll
        for (int nt = 0; nt < 4; ++nt) {
#pragma unroll
            for (int j = 0; j < 4; ++j) {
                const int lr = wm * 64 + mt * 16 + ((lane >> 4) << 2) + j;
                const int cc = wn * 64 + nt * 16 + (lane & 15);
                const long rg = (long)by * 128 + lr;
                const long b = rg & 63;
                const long t = (rg >> 6) * 8 + k;
                obs[b * 262144L + t * 256 + cc] = acc2[mt][nt][j];
            }
        }
    }
#undef BS1
#undef AS1
}

// f32 -> bf16 bulk conversion, 8 elems/thread.
__global__ void cvt_k(const float* src, unsigned short* dst, long n) {
    long i = ((long)blockIdx.x * 256 + threadIdx.x) * 8;
    const long stride = (long)gridDim.x * 256 * 8;
    for (; i < n; i += stride) {
        f32x4 x0 = *(const f32x4*)(src + i), x1 = *(const f32x4*)(src + i + 4);
        union { bfrag v; unsigned short h[8]; } t;
#pragma unroll
        for (int q = 0; q < 4; ++q) { t.h[q] = f2bf(x0[q]); t.h[4 + q] = f2bf(x1[q]); }
        *(bfrag*)(dst + i) = t.v;
    }
}

// Build bf16 operators: BopD (512x768)=[B_mat|sqrt_S_W], BopO (256x768)=[H|sqrt_S_V],
// G[0]=F, Gt[0]=F^T.
__global__ void build_ops_k(const float* F, const float* Bm, const float* H,
                            const float* sW, const float* sV,
                            unsigned short* bopd, unsigned short* bopo,
                            unsigned short* G1, unsigned short* Gt1) {
    int i = blockIdx.x * 256 + threadIdx.x;
    const int n1 = 512 * 768, n2 = 256 * 768, n3 = 512 * 512;
    if (i < n1) { int n = i / 768, k = i % 768;
        bopd[i] = f2bf(k < 256 ? Bm[n * 256 + k] : sW[n * 512 + (k - 256)]); return; }
    i -= n1;
    if (i < n2) { int o = i / 768, k = i % 768;
        bopo[i] = f2bf(k < 512 ? H[o * 512 + k] : sV[o * 256 + (k - 512)]); return; }
    i -= n2;
    if (i < n3) { G1[i] = f2bf(F[i]); return; }
    i -= n3;
    if (i < n3) { int r = i / 512, c = i % 512; Gt1[i] = f2bf(F[c * 512 + r]); }
}

// Initial carries: dst[c*32768 + b*512 + s]; c==0 from st0 (f32), else from
// Smir local[c-1, 7] = Smir[b*524288 + (c-1)*4096 + 3584 + s].
__global__ void init_carry_k(const float* st0, const unsigned short* Smir,
                             unsigned short* dst) {
    const long i8 = ((long)blockIdx.x * 256 + threadIdx.x) * 8;  // 4,194,304 total
    if (i8 >= 4194304L) return;
    const long c = i8 >> 15, rem = i8 & 32767L;
    const long b = rem >> 9, s = rem & 511L;
    union { bfrag v; unsigned short h[8]; } t;
    if (c == 0) {
        const float* p = st0 + b * 512 + s;
        f32x4 x0 = *(const f32x4*)p, x1 = *(const f32x4*)(p + 4);
#pragma unroll
        for (int q = 0; q < 4; ++q) { t.h[q] = f2bf(x0[q]); t.h[4 + q] = f2bf(x1[q]); }
    } else {
        t.v = *(const bfrag*)(Smir + b * 524288L + (c - 1) * 4096L + 3584L + s);
    }
    *(bfrag*)(dst + i8) = t.v;
}

static GemmDesc D0() {
    GemmDesc d = {};
    d.zdivl = 30;
    d.ksplit = 1 << 30;
    d.b_ldb = 512; d.K = 512;
    d.gz_main = 1 << 30;
    return d;
}

extern "C" void kernel_launch(void* const* d_in, const int* in_sizes, int n_in,
                              void* d_out, int out_size, void* d_ws, size_t ws_size,
                              hipStream_t stream) {
    const float* st0 = (const float*)d_in[0];
    const float* inp = (const float*)d_in[1];
    const float* Wn  = (const float*)d_in[2];
    const float* Vn  = (const float*)d_in[3];
    const float* F   = (const float*)d_in[4];
    const float* Bm  = (const float*)d_in[5];
    const float* H   = (const float*)d_in[6];
    const float* sW  = (const float*)d_in[7];
    const float* sV  = (const float*)d_in[8];

    float* states = (float*)d_out;              // (64,1024,512) f32
    float* obs    = states + 33554432L;         // (64,1024,256) f32

    const long MS = MSL;
    const long CB = 32768;    // 64*512 per-chunk carry block
    const int  NC = 128;      // chunks
    const long TOS = 524288;  // batch stride
    const long COS = 4096;    // chunk stride within batch row

    // d_out states region: inp/Wn bf16 scratch (dead after drive), then BufA
    // ping buffer for phase1 rounds 1-2 (dead after r2), then states (p3obs).
    unsigned short* inpb = (unsigned short*)states;
    unsigned short* Wnb  = inpb + 16777216L;
    unsigned short* BufA = (unsigned short*)states;        // 33,554,432 shorts

    // ws layout (all bf16 bits)
    unsigned short* Smir = (unsigned short*)d_ws;          // 33,554,432
    unsigned short* G    = Smir + 33554432L;               // G[j]=F^{j+1}, j=0..7
    unsigned short* Gt   = G + 8 * MS;
    unsigned short* Qb   = Gt + 8 * MS;                    // F^{16*2^j}, j=0..5
    unsigned short* Qtb  = Qb + 6 * MS;                    // j=0..4 (+1 spare)
    unsigned short* BopD = Qtb + 6 * MS;                   // 512*768
    unsigned short* BopO = BopD + 512 * 768;               // 256*768
    unsigned short* a0m  = BopO + 256 * 768;               // NC*CB carries
    unsigned short* a1m  = a0m + (long)NC * CB;
    (void)in_sizes; (void)n_in; (void)out_size; (void)ws_size;

    auto L = [&](const GemmDesc& d, int gx, int gxl, int gy, int gyl, int gz) {
        GemmDesc dd = d; dd.gxl = gxl; dd.gyl = gyl;
        gemm_k<<<dim3(gx, gy, gz), dim3(256), 0, stream>>>(dd);
    };

    // 0) bf16 prepass
    cvt_k<<<dim3(2048), dim3(256), 0, stream>>>(inp, inpb, 16777216L);
    cvt_k<<<dim3(2048), dim3(256), 0, stream>>>(Wn, Wnb, 33554432L);

    // 1) operators + F, F^T
    build_ops_k<<<dim3(4352), dim3(256), 0, stream>>>(F, Bm, H, sW, sV, BopD, BopO, G, Gt);

    // 2) drive = [inputs | W_noise] @ BopD^T -> Smir ; aux: F^2
    {
        GemmDesc d = D0();
        d.a0 = inpb; d.a0_os = 256;
        d.a1 = Wnb;  d.a1_os = 512;
        d.ksplit = 256; d.K = 768;
        d.b = BopD; d.b_ldb = 768;
        d.cm = Smir; d.c_os = 512;
        d.gz_main = 1;
        d.xa = G; d.xb = Gt; d.xcm = G + MS; d.xcmT = Gt + MS;
        L(d, 4, 2, 512, 9, 2);
    }

    // 3) phase 1 as 3-round Kogge-Stone within chunks.
    // r1: BufA[t] = Smir[t-1]@F^T + Smir[t], t=1..7 (z=0..6); copy t=0; aux F^3,F^4
    {
        GemmDesc d = D0();
        d.a0 = Smir; d.a0_icl = 7; d.a0_os = TOS; d.a0_is = COS; d.a_zr = 512;
        d.b = G;                                   // F
        d.cm = BufA; d.cm_base = 512;
        d.c_icl = 7; d.c_os = TOS; d.c_is = COS; d.c_zr = 512;
        d.beta = 2; d.cmbeta = Smir; d.cmb_base = 512;
        d.gz_main = 7; d.gz_ncp = 1;
        d.cp_src = Smir; d.cp_dst = BufA; d.cp_nrows = 8192;
        d.xa = G; d.xb = Gt + MS; d.xcm = G + 2 * MS; d.xcmT = Gt + 2 * MS;
        L(d, 4, 2, 64, 6, 10);
    }
    // r2: Smir[t] = BufA[t-2]@(F^2)^T + BufA[t], t=2..7 (z=0..5); copy t=0,1; aux F^5..F^8
    {
        GemmDesc d = D0();
        d.a0 = BufA; d.a0_icl = 7; d.a0_os = TOS; d.a0_is = COS; d.a_zr = 512;
        d.b = G + MS;                              // F^2
        d.cm = Smir; d.cm_base = 1024;
        d.c_icl = 7; d.c_os = TOS; d.c_is = COS; d.c_zr = 512;
        d.beta = 2; d.cmbeta = BufA; d.cmb_base = 1024;
        d.gz_main = 6; d.gz_ncp = 1;
        d.cp_src = BufA; d.cp_dst = Smir; d.cp_nrows = 16384;
        d.xa = G; d.xb = Gt + 3 * MS; d.xcm = G + 4 * MS; d.xcmT = Gt + 4 * MS;
        L(d, 4, 2, 64, 6, 11);
    }
    // r3 (in-place, disjoint): Smir[t] += Smir[t-4]@(F^4)^T, t=4..7 (z=0..3); aux F^16
    {
        GemmDesc d = D0();
        d.a0 = Smir; d.a0_icl = 7; d.a0_os = TOS; d.a0_is = COS; d.a_zr = 512;
        d.b = G + 3 * MS;                          // F^4
        d.cm = Smir; d.cm_base = 2048;
        d.c_icl = 7; d.c_os = TOS; d.c_is = COS; d.c_zr = 512;
        d.beta = 2; d.cmbeta = Smir; d.cmb_base = 2048;
        d.gz_main = 4;
        d.xa = G + 7 * MS; d.xb = Gt + 7 * MS; d.xcm = Qb; d.xcmT = Qtb;
        L(d, 4, 2, 64, 6, 5);
    }

    // 4) initial carries
    init_carry_k<<<dim3(2048), dim3(256), 0, stream>>>(st0, Smir, a0m);

    // 5) Kogge-Stone over chunks (7 rounds); aux doubles F^32..F^512
    unsigned short* curm = a0m;
    unsigned short* nxtm = a1m;
    int ksi = 0;
    for (int s = 1; s < NC; s <<= 1, ++ksi) {
        GemmDesc d = D0();
        d.a0 = curm; d.a0_os = 512;
        d.a_shift = (long)s * 64;
        if (s == 1) { d.b = G + 7 * MS; }                                // F^8
        else        { d.b = Qb + (long)(__builtin_ctz(s) - 1) * MS; }    // F^{8s}
        d.beta = 2; d.cmbeta = curm; d.cmb_base = 0;
        d.cm = nxtm; d.c_os = 512;
        int n = 0;
        if (ksi < 5) {                       // aux: Qb[ksi+1] = Qb[ksi]^2
            d.gz_main = 1;
            d.xa = Qb + (long)ksi * MS; d.xb = Qtb + (long)ksi * MS;
            d.xcm = Qb + (long)(ksi + 1) * MS;
            d.xcmT = (ksi < 4) ? (Qtb + (long)(ksi + 1) * MS) : nullptr;
            n = 1;
        }
        L(d, 4, 2, 64, 6, 1 + n);
        unsigned short* tm = curm; curm = nxtm; nxtm = tm;
    }
    // after 7 rounds: curm = a1m

    // 6) fused phase3 + obs (x = k so each XCD owns one G[k])
    p3obs_k<<<dim3(8, 64, 1), dim3(512), 0, stream>>>(
        curm, G, Smir, BopO, Vn, states, obs);
}

// Round 11
// 867.879 us; speedup vs baseline: 1.0838x; 1.0838x over previous
//
#include <hip/hip_runtime.h>
#include <hip/hip_bf16.h>

// ---------------------------------------------------------------------------
// LinearSystem: chunked parallel scan, bf16 MFMA. Round 11 = R8 structure
// (best, 703us) with CL=4 / NC=256 re-chunk: phase1 7->3 sequential launches
// (same FLOPs, 2x occupancy), KS 7->8 rounds (bigger M per round), power
// chain rescheduled (G: F..F^4; Qb: F^8..F^512). p3obs identical to R8 but
// grid (1,128,4), t = c*4+k.
// ---------------------------------------------------------------------------

typedef short bfrag __attribute__((ext_vector_type(8)));   // 8 x bf16 bits
typedef float f32x4 __attribute__((ext_vector_type(4)));

__device__ __host__ inline unsigned short f2bf(float f) {
    union { float f; unsigned u; } x; x.f = f;
    unsigned r = x.u + 0x7fffu + ((x.u >> 16) & 1u);   // RNE
    return (unsigned short)(r >> 16);
}
__device__ inline float bf2f(unsigned short h) {
    union { unsigned u; float f; } x; x.u = ((unsigned)h) << 16;
    return x.f;
}

#define MSL 262144L   // 512*512 matrix stride

struct GemmDesc {
    const unsigned short* a0; const unsigned short* a1;  // A (k < ksplit -> a0)
    const unsigned short* b;                 // B, bf16, (N,K) row-major (B^T)
    float* c;                                // f32 C out (nullable)
    const unsigned short* cmbeta;            // bf16 beta source (beta==2)
    unsigned short* cm;                      // bf16 mirror out (nullable)
    unsigned short* cmT;                     // bf16 transposed mirror (512x512)
    long a0_base, a0_os, a0_is;              // row map: (r>>icl)*os + (r&mask)*is
    long a1_base, a1_os, a1_is;
    long a_zq, a_zr;
    long b_base, b_ldb, b_zq, b_zr;
    long c_base, c_os, c_is, c_zq, c_zr;
    long cm_base, cmb_base, cmT_base;
    long a_shift;                            // prefix rows (copy-only, acc=0)
    int a0_icl, a1_icl, c_icl, zdivl;
    int ksplit, K, beta;                     // beta: 0 none, 2 bf16 cmbeta
    int gxl, gyl, gz_main;
    // aux power-chain slice (bz >= gz_main): 512x512 C = xa[z] @ xb^T
    const unsigned short* xa; const unsigned short* xb;
    unsigned short* xcm; unsigned short* xcmT;
};

// 128x128 tile, BK=64, 4 waves (2x2 of 64x64), double-buffered 2-phase.
__global__ __launch_bounds__(256) void gemm_k(GemmDesc d) {
    __shared__ __align__(16) unsigned short As[2][128 * 64];
    __shared__ __align__(16) unsigned short Bs[2][128 * 64];
    const int tid  = threadIdx.x;
    const int lane = tid & 63;
    const int w    = tid >> 6;
    const int wrow = (w >> 1) * 64, wcol = (w & 1) * 64;

    // flattened grid + XCD-chunked bijective swizzle (x fastest)
    const unsigned nx = gridDim.x, ny = gridDim.y;
    const unsigned nwg = nx * ny * gridDim.z;
    unsigned wid = blockIdx.x + nx * (blockIdx.y + ny * blockIdx.z);
    if ((nwg & 7) == 0) wid = (wid & 7) * (nwg >> 3) + (wid >> 3);
    const int bx = wid & (nx - 1);
    const int by = (wid >> d.gxl) & (ny - 1);
    int bz = wid >> (d.gxl + d.gyl);

    if (bz >= d.gz_main) {                   // aux: 512x512 power-chain GEMM
        if (by >= 4) return;
        const long za = (long)(bz - d.gz_main) * MSL;
        d.a0 = d.xa; d.a0_base = za; d.a0_os = 512; d.a0_is = 0; d.a0_icl = 0;
        d.a1 = nullptr;
        d.b = d.xb; d.b_base = 0; d.b_ldb = 512; d.b_zq = d.b_zr = 0;
        d.K = 512; d.ksplit = 1 << 30; d.beta = 0; d.a_shift = 0;
        d.a_zq = d.a_zr = 0;
        d.c = nullptr; d.cm = d.xcm; d.cm_base = za;
        d.c_os = 512; d.c_is = 0; d.c_icl = 0; d.c_zq = d.c_zr = 0; d.c_base = 0;
        d.cmT = d.xcmT; d.cmT_base = za;
        bz = 0;
    }
    const long zq = (long)bz >> d.zdivl;
    const long zr = (long)bz & ((1L << d.zdivl) - 1);
    const int row0 = by * 128;
    const int col0 = bx * 128;

    const int g_r = tid >> 3;                // staging row within 32-row group
    const int g_k = (tid & 7) * 8;           // 16B k-slot
    const int swz = (g_r & 7) << 3;          // XOR swizzle (8-elem units)
    const long za_ = zq * d.a_zq + zr * d.a_zr;
    const long zb_ = zq * d.b_zq + zr * d.b_zr;

    const long m0a = (1L << d.a0_icl) - 1, m1a = (1L << d.a1_icl) - 1;
    long a0off[4], a1off[4], boff[4];
#pragma unroll
    for (int i = 0; i < 4; ++i) {
        long ar = (long)row0 + i * 32 + g_r - d.a_shift;
        if (ar < 0) ar = 0;
        a0off[i] = d.a0_base + za_ + (ar >> d.a0_icl) * d.a0_os + (ar & m0a) * d.a0_is;
        a1off[i] = d.a1 ? (d.a1_base + za_ + (ar >> d.a1_icl) * d.a1_os + (ar & m1a) * d.a1_is) : 0;
        boff[i]  = d.b_base + zb_ + (long)(col0 + i * 32 + g_r) * d.b_ldb;
    }

    bfrag ar_[4], br_[4];
    auto LOADT = [&](int t) {
        const int k0 = t * 64;
        const bool s1 = (k0 >= d.ksplit);
        const int kb = (s1 ? k0 - d.ksplit : k0) + g_k;
        const unsigned short* sp = s1 ? d.a1 : d.a0;
#pragma unroll
        for (int i = 0; i < 4; ++i)
            ar_[i] = *(const bfrag*)(sp + (s1 ? a1off[i] : a0off[i]) + kb);
#pragma unroll
        for (int i = 0; i < 4; ++i) br_[i] = *(const bfrag*)(d.b + boff[i] + k0 + g_k);
    };
    auto WRT = [&](int buf) {
#pragma unroll
        for (int i = 0; i < 4; ++i) {
            *(bfrag*)&As[buf][(i * 32 + g_r) * 64 + (g_k ^ swz)] = ar_[i];
            *(bfrag*)&Bs[buf][(i * 32 + g_r) * 64 + (g_k ^ swz)] = br_[i];
        }
    };

    f32x4 acc[4][4] = {};
    const int nt = d.K / 64;

    LOADT(0); WRT(0); __syncthreads();
    int cur = 0;
    for (int t = 0; t < nt; ++t) {
        if (t + 1 < nt) LOADT(t + 1);        // issue next-tile loads early
#pragma unroll
        for (int ks = 0; ks < 2; ++ks) {
            const int kk = ks * 32 + (lane >> 4) * 8;
            bfrag af[4], bf_[4];
#pragma unroll
            for (int mt = 0; mt < 4; ++mt) {
                const int r = wrow + mt * 16 + (lane & 15);
                af[mt] = *(const bfrag*)&As[cur][r * 64 + (kk ^ ((r & 7) << 3))];
            }
#pragma unroll
            for (int nn = 0; nn < 4; ++nn) {
                const int r = wcol + nn * 16 + (lane & 15);
                bf_[nn] = *(const bfrag*)&Bs[cur][r * 64 + (kk ^ ((r & 7) << 3))];
            }
#pragma unroll
            for (int mt = 0; mt < 4; ++mt)
#pragma unroll
                for (int nn = 0; nn < 4; ++nn)
                    acc[mt][nn] = __builtin_amdgcn_mfma_f32_16x16x32_bf16(
                        af[mt], bf_[nn], acc[mt][nn], 0, 0, 0);
        }
        if (t + 1 < nt) WRT(cur ^ 1);        // write-late (hidden under compute)
        __syncthreads();                     // ONE barrier per K-step
        cur ^= 1;
    }

    // ---- epilogue: C/D layout col=lane&15, row=(lane>>4)*4+j ----
    const long zc = zq * d.c_zq + zr * d.c_zr;
    const long mc = (1L << d.c_icl) - 1;
#pragma unroll
    for (int mt = 0; mt < 4; ++mt) {
        const int rb = row0 + wrow + mt * 16 + ((lane >> 4) << 2);
#pragma unroll
        for (int nn = 0; nn < 4; ++nn) {
            const int cc = col0 + wcol + nn * 16 + (lane & 15);
#pragma unroll
            for (int j = 0; j < 4; ++j) {
                const long r = rb + j;
                const long off = zc + (r >> d.c_icl) * d.c_os + (r & mc) * d.c_is + cc;
                float v = (r < d.a_shift) ? 0.0f : acc[mt][nn][j];
                if (d.beta == 2) v += bf2f(d.cmbeta[d.cmb_base + off]);
                if (d.c)  d.c[d.c_base + off] = v;
                if (d.cm) d.cm[d.cm_base + off] = f2bf(v);
                if (d.cmT) d.cmT[d.cmT_base + zc + (long)cc * 512 + r] = f2bf(v);
            }
        }
    }
}

// ---------------------------------------------------------------------------
// Fused phase3 + obs (R8 version). Grid (1, 128, 4): y = 128-row tile over
// (c,b) rows, z = k (step within 4-long chunk). 512 threads, 160 KiB LDS.
//   GEMM1: s[128x512] = carry @ (F^{k+1})^T; +local, write states f32,
//          deposit bf16 rows into LDS Sb.
//   GEMM2: obs[128x256] = [Sb | cvt(Vn)] @ BopO^T; write obs f32.
// ---------------------------------------------------------------------------
__global__ __launch_bounds__(512) void p3obs_k(
        const unsigned short* __restrict__ carry, const unsigned short* __restrict__ Gm,
        const unsigned short* __restrict__ Smir, const unsigned short* __restrict__ BopO,
        const float* __restrict__ Vn, float* __restrict__ states, float* __restrict__ obs) {
    __shared__ __align__(16) unsigned char lds[163840];
    unsigned short* As1 = (unsigned short*)(lds);            // [128][64]  (phase A)
    unsigned short* Bs1 = (unsigned short*)(lds + 16384);    // [512][64]  (phase A)
    unsigned short* Sb  = (unsigned short*)(lds);            // [128][512] (phase B)
    unsigned short* A2  = (unsigned short*)(lds);            // [128][64]  (B2, over Sb)
    unsigned short* Ts  = (unsigned short*)(lds + 131072);   // [256][64]  (phase B)

    const int tid  = threadIdx.x;
    const int lane = tid & 63;
    const int w    = tid >> 6;               // 0..7
    const int wm   = w >> 2, wn = w & 3;     // 2 x 4 wave grid
    const int by   = blockIdx.y;             // 0..127
    const int k    = blockIdx.z;             // 0..3
    const unsigned short* G = Gm + (long)k * MSL;   // F^{k+1}, (512,512) row-major

    f32x4 acc[4][8] = {};

    // ---------- GEMM1 ----------
    for (int kt = 0; kt < 8; ++kt) {
        __syncthreads();
#pragma unroll
        for (int i = 0; i < 2; ++i) {        // A tile: carry rows
            const int fi = tid + i * 512;
            const int row = fi >> 3, kk = (fi & 7) * 8;
            const long rg = (long)by * 128 + row;
            const long c = rg >> 6, b = rg & 63;
            bfrag v = *(const bfrag*)(carry + c * 32768 + b * 512 + kt * 64 + kk);
            *(bfrag*)&As1[row * 64 + (kk ^ ((row & 7) << 3))] = v;
        }
#pragma unroll
        for (int i = 0; i < 8; ++i) {        // B tile: G rows (all 512)
            const int fi = tid + i * 512;
            const int row = fi >> 3, kk = (fi & 7) * 8;
            bfrag v = *(const bfrag*)(G + (long)row * 512 + kt * 64 + kk);
            *(bfrag*)&Bs1[row * 64 + (kk ^ ((row & 7) << 3))] = v;
        }
        __syncthreads();
#pragma unroll
        for (int ks = 0; ks < 2; ++ks) {
            const int kk = ks * 32 + (lane >> 4) * 8;
            bfrag af[4], bf_[8];
#pragma unroll
            for (int mt = 0; mt < 4; ++mt) {
                const int r = wm * 64 + mt * 16 + (lane & 15);
                af[mt] = *(const bfrag*)&As1[r * 64 + (kk ^ ((r & 7) << 3))];
            }
#pragma unroll
            for (int nt = 0; nt < 8; ++nt) {
                const int n = wn * 128 + nt * 16 + (lane & 15);
                bf_[nt] = *(const bfrag*)&Bs1[n * 64 + (kk ^ ((n & 7) << 3))];
            }
#pragma unroll
            for (int mt = 0; mt < 4; ++mt)
#pragma unroll
                for (int nt = 0; nt < 8; ++nt)
                    acc[mt][nt] = __builtin_amdgcn_mfma_f32_16x16x32_bf16(
                        af[mt], bf_[nt], acc[mt][nt], 0, 0, 0);
        }
    }
    __syncthreads();                          // As1/Bs1 dead; Sb about to be written

    // ---------- epilogue 1: +local, write states, build Sb ----------
#pragma unroll
    for (int mt = 0; mt < 4; ++mt) {
#pragma unroll
        for (int nt = 0; nt < 8; ++nt) {
#pragma unroll
            for (int j = 0; j < 4; ++j) {
                const int lr = wm * 64 + mt * 16 + ((lane >> 4) << 2) + j;
                const int cc = wn * 128 + nt * 16 + (lane & 15);
                const long rg = (long)by * 128 + lr;
                const long c = rg >> 6, b = rg & 63;
                const long t = c * 4 + k;
                float v = acc[mt][nt][j] + bf2f(Smir[b * 524288L + t * 512 + cc]);
                states[b * 524288L + t * 512 + cc] = v;
                Sb[lr * 512 + (cc ^ ((lr & 7) << 3))] = f2bf(v);
            }
        }
    }

    // ---------- GEMM2: obs = [Sb | Vn] @ BopO^T ----------
    f32x4 acc2[4][4] = {};
    for (int kt = 0; kt < 12; ++kt) {
        __syncthreads();
#pragma unroll
        for (int i = 0; i < 4; ++i) {        // Ts: BopO rows 0..255
            const int fi = tid + i * 512;
            const int row = fi >> 3, kk = (fi & 7) * 8;
            bfrag v = *(const bfrag*)(BopO + (long)row * 768 + kt * 64 + kk);
            *(bfrag*)&Ts[row * 64 + (kk ^ ((row & 7) << 3))] = v;
        }
        if (kt >= 8) {
#pragma unroll
            for (int i = 0; i < 2; ++i) {    // A2: Vn f32 -> bf16
                const int fi = tid + i * 512;
                const int row = fi >> 3, kk = (fi & 7) * 8;
                const long rg = (long)by * 128 + row;
                const long c = rg >> 6, b = rg & 63;
                const long t = c * 4 + k;
                const float* p = Vn + b * 262144L + t * 256 + (kt - 8) * 64 + kk;
                f32x4 x0 = *(const f32x4*)p, x1 = *(const f32x4*)(p + 4);
                union { bfrag v; unsigned short h[8]; } u;
#pragma unroll
                for (int q = 0; q < 4; ++q) { u.h[q] = f2bf(x0[q]); u.h[4 + q] = f2bf(x1[q]); }
                *(bfrag*)&A2[row * 64 + (kk ^ ((row & 7) << 3))] = u.v;
            }
        }
        __syncthreads();
#pragma unroll
        for (int ks = 0; ks < 2; ++ks) {
            const int kk = ks * 32 + (lane >> 4) * 8;
            bfrag af[4], bf_[4];
#pragma unroll
            for (int mt = 0; mt < 4; ++mt) {
                const int r = wm * 64 + mt * 16 + (lane & 15);
                af[mt] = (kt < 8)
                    ? *(const bfrag*)&Sb[r * 512 + ((kt * 64 + kk) ^ ((r & 7) << 3))]
                    : *(const bfrag*)&A2[r * 64 + (kk ^ ((r & 7) << 3))];
            }
#pragma unroll
            for (int nt = 0; nt < 4; ++nt) {
                const int n = wn * 64 + nt * 16 + (lane & 15);
                bf_[nt] = *(const bfrag*)&Ts[n * 64 + (kk ^ ((n & 7) << 3))];
            }
#pragma unroll
            for (int mt = 0; mt < 4; ++mt)
#pragma unroll
                for (int nt = 0; nt < 4; ++nt)
                    acc2[mt][nt] = __builtin_amdgcn_mfma_f32_16x16x32_bf16(
                        af[mt], bf_[nt], acc2[mt][nt], 0, 0, 0);
        }
    }
    // ---------- epilogue 2: write obs ----------
#pragma unroll
    for (int mt = 0; mt < 4; ++mt) {
#pragma unroll
        for (int nt = 0; nt < 4; ++nt) {
#pragma unroll
            for (int j = 0; j < 4; ++j) {
                const int lr = wm * 64 + mt * 16 + ((lane >> 4) << 2) + j;
                const int cc = wn * 64 + nt * 16 + (lane & 15);
                const long rg = (long)by * 128 + lr;
                const long c = rg >> 6, b = rg & 63;
                const long t = c * 4 + k;
                obs[b * 262144L + t * 256 + cc] = acc2[mt][nt][j];
            }
        }
    }
}

// f32 -> bf16 bulk conversion, 8 elems/thread.
__global__ void cvt_k(const float* src, unsigned short* dst, long n) {
    long i = ((long)blockIdx.x * 256 + threadIdx.x) * 8;
    const long stride = (long)gridDim.x * 256 * 8;
    for (; i < n; i += stride) {
        f32x4 x0 = *(const f32x4*)(src + i), x1 = *(const f32x4*)(src + i + 4);
        union { bfrag v; unsigned short h[8]; } t;
#pragma unroll
        for (int q = 0; q < 4; ++q) { t.h[q] = f2bf(x0[q]); t.h[4 + q] = f2bf(x1[q]); }
        *(bfrag*)(dst + i) = t.v;
    }
}

// Build bf16 operators: BopD (512x768)=[B_mat|sqrt_S_W], BopO (256x768)=[H|sqrt_S_V],
// G[0]=F, Gt[0]=F^T.
__global__ void build_ops_k(const float* F, const float* Bm, const float* H,
                            const float* sW, const float* sV,
                            unsigned short* bopd, unsigned short* bopo,
                            unsigned short* G1, unsigned short* Gt1) {
    int i = blockIdx.x * 256 + threadIdx.x;
    const int n1 = 512 * 768, n2 = 256 * 768, n3 = 512 * 512;
    if (i < n1) { int n = i / 768, k = i % 768;
        bopd[i] = f2bf(k < 256 ? Bm[n * 256 + k] : sW[n * 512 + (k - 256)]); return; }
    i -= n1;
    if (i < n2) { int o = i / 768, k = i % 768;
        bopo[i] = f2bf(k < 512 ? H[o * 512 + k] : sV[o * 256 + (k - 512)]); return; }
    i -= n2;
    if (i < n3) { G1[i] = f2bf(F[i]); return; }
    i -= n3;
    if (i < n3) { int r = i / 512, c = i % 512; Gt1[i] = f2bf(F[c * 512 + r]); }
}

// Initial carries (NC=256): dst[c*32768 + b*512 + s]; c==0 from st0 (f32),
// else from Smir local[c-1, 3] = Smir[b*524288 + (c-1)*2048 + 1536 + s].
__global__ void init_carry_k(const float* st0, const unsigned short* Smir,
                             unsigned short* dst) {
    const long i8 = ((long)blockIdx.x * 256 + threadIdx.x) * 8;  // 8,388,608 total
    if (i8 >= 8388608L) return;
    const long c = i8 >> 15, rem = i8 & 32767L;
    const long b = rem >> 9, s = rem & 511L;
    union { bfrag v; unsigned short h[8]; } t;
    if (c == 0) {
        const float* p = st0 + b * 512 + s;
        f32x4 x0 = *(const f32x4*)p, x1 = *(const f32x4*)(p + 4);
#pragma unroll
        for (int q = 0; q < 4; ++q) { t.h[q] = f2bf(x0[q]); t.h[4 + q] = f2bf(x1[q]); }
    } else {
        t.v = *(const bfrag*)(Smir + b * 524288L + (c - 1) * 2048L + 1536L + s);
    }
    *(bfrag*)(dst + i8) = t.v;
}

static GemmDesc D0() {
    GemmDesc d = {};
    d.zdivl = 30;
    d.ksplit = 1 << 30;
    d.b_ldb = 512; d.K = 512;
    d.gz_main = 1 << 30;
    return d;
}

extern "C" void kernel_launch(void* const* d_in, const int* in_sizes, int n_in,
                              void* d_out, int out_size, void* d_ws, size_t ws_size,
                              hipStream_t stream) {
    const float* st0 = (const float*)d_in[0];
    const float* inp = (const float*)d_in[1];
    const float* Wn  = (const float*)d_in[2];
    const float* Vn  = (const float*)d_in[3];
    const float* F   = (const float*)d_in[4];
    const float* Bm  = (const float*)d_in[5];
    const float* H   = (const float*)d_in[6];
    const float* sW  = (const float*)d_in[7];
    const float* sV  = (const float*)d_in[8];

    float* states = (float*)d_out;              // (64,1024,512) f32
    float* obs    = states + 33554432L;         // (64,1024,256) f32

    const long MS = MSL;
    const long CB = 32768;    // 64*512 per-chunk carry block
    const int  NC = 256;      // chunks
    const int  CL = 4;        // chunk length
    const long TOS = 524288;  // batch stride
    const long COS = (long)CL * 512;   // chunk stride = 2048

    // d_out states region: inp/Wn bf16 scratch (dead after drive).
    unsigned short* inpb = (unsigned short*)states;
    unsigned short* Wnb  = inpb + 16777216L;

    // ws layout (all bf16 bits)
    unsigned short* Smir = (unsigned short*)d_ws;          // 33,554,432
    unsigned short* G    = Smir + 33554432L;               // G[j]=F^{j+1}, j=0..3
    unsigned short* Gt   = G + 4 * MS;
    unsigned short* Qb   = Gt + 4 * MS;                    // Qb[j]=F^{8*2^j}, j=0..6
    unsigned short* Qtb  = Qb + 7 * MS;                    // j=0..5
    unsigned short* BopD = Qtb + 6 * MS;                   // 512*768
    unsigned short* BopO = BopD + 512 * 768;               // 256*768
    unsigned short* a0m  = BopO + 256 * 768;               // NC*CB carries (8M ea)
    unsigned short* a1m  = a0m + (long)NC * CB;
    (void)in_sizes; (void)n_in; (void)out_size; (void)ws_size;

    auto L = [&](const GemmDesc& d, int gx, int gxl, int gy, int gyl, int gz) {
        GemmDesc dd = d; dd.gxl = gxl; dd.gyl = gyl;
        gemm_k<<<dim3(gx, gy, gz), dim3(256), 0, stream>>>(dd);
    };

    // 0) bf16 prepass: inp, Wn -> d_out scratch
    cvt_k<<<dim3(2048), dim3(256), 0, stream>>>(inp, inpb, 16777216L);
    cvt_k<<<dim3(2048), dim3(256), 0, stream>>>(Wn, Wnb, 33554432L);

    // 1) operators + F, F^T
    build_ops_k<<<dim3(4352), dim3(256), 0, stream>>>(F, Bm, H, sW, sV, BopD, BopO, G, Gt);

    // 2) drive = [inputs | W_noise] @ BopD^T -> Smir ; aux: F^2 (+T)
    {
        GemmDesc d = D0();
        d.a0 = inpb; d.a0_os = 256;
        d.a1 = Wnb;  d.a1_os = 512;
        d.ksplit = 256; d.K = 768;
        d.b = BopD; d.b_ldb = 768;
        d.cm = Smir; d.c_os = 512;
        d.gz_main = 1;
        d.xa = G; d.xb = Gt; d.xcm = G + MS; d.xcmT = Gt + MS;
        L(d, 4, 2, 512, 9, 2);
    }

    // 3) phase 1: 3 sequential steps (M = 64*256 = 16384 rows each, in-place).
    //    rows r=(b,c): icl=8, os=TOS, is=COS. Smir[t] += Smir[t-1] @ F^T.
    //    aux: k=1 -> F^3 = F@F^2, F^4 = F^2@F^2 (xa z-strided from G[0], xb=Gt[1]);
    //         k=2 -> Qb[0]=F^8 (+T); k=3 -> Qb[1]=F^16 (+T)
    for (int k = 1; k < CL; ++k) {
        GemmDesc d = D0();
        d.a0 = Smir; d.a0_base = (long)(k - 1) * 512;
        d.a0_icl = 8; d.a0_is = COS; d.a0_os = TOS;
        d.b = G;  // F
        d.c_base = (long)k * 512;
        d.c_icl = 8; d.c_is = COS; d.c_os = TOS;
        d.beta = 2; d.cmbeta = Smir; d.cmb_base = (long)k * 512;
        d.cm = Smir; d.cm_base = (long)k * 512;
        d.gz_main = 1;
        int n;
        if (k == 1)      { d.xa = G;          d.xb = Gt + MS;     d.xcm = G + 2 * MS; d.xcmT = Gt + 2 * MS; n = 2; }
        else if (k == 2) { d.xa = G + 3 * MS; d.xb = Gt + 3 * MS; d.xcm = Qb;         d.xcmT = Qtb;         n = 1; }
        else             { d.xa = Qb;         d.xb = Qtb;         d.xcm = Qb + MS;    d.xcmT = Qtb + MS;    n = 1; }
        L(d, 4, 2, 128, 7, 1 + n);
    }

    // 4) initial carries (256 chunks)
    init_carry_k<<<dim3(4096), dim3(256), 0, stream>>>(st0, Smir, a0m);

    // 5) Kogge-Stone over chunks, 8 rounds s=1..128:
    //    nxt[r] = cur[r] + (r>=s*64 ? cur[r-s*64]@(F^{4s})^T : 0)
    //    F^{4s}: s=1 -> G[3]=F^4; s=2^m (m>=1) -> Qb[m-1].
    //    aux rounds ri=0..4: Qb[ri+2] = Qb[ri+1]^2 (+T for ri<4)
    unsigned short* curm = a0m;
    unsigned short* nxtm = a1m;
    int ri = 0;
    for (int s = 1; s < NC; s <<= 1, ++ri) {
        GemmDesc d = D0();
        d.a0 = curm; d.a0_os = 512;
        d.a_shift = (long)s * 64;
        if (s == 1) { d.b = G + 3 * MS; }                                // F^4
        else        { d.b = Qb + (long)(__builtin_ctz(s) - 1) * MS; }    // F^{4s}
        d.beta = 2; d.cmbeta = curm; d.cmb_base = 0;
        d.cm = nxtm; d.c_os = 512;
        int n = 0;
        if (ri < 5) {                        // aux: Qb[ri+2] = Qb[ri+1]@Qtb[ri+1]
            d.gz_main = 1;
            d.xa = Qb + (long)(ri + 1) * MS; d.xb = Qtb + (long)(ri + 1) * MS;
            d.xcm = Qb + (long)(ri + 2) * MS;
            d.xcmT = (ri < 4) ? (Qtb + (long)(ri + 2) * MS) : nullptr;
            n = 1;
        }
        L(d, 4, 2, 128, 7, 1 + n);
        unsigned short* tm = curm; curm = nxtm; nxtm = tm;
    }
    // after 8 rounds: curm = a0m

    // 6) fused phase3 + obs
    p3obs_k<<<dim3(1, 128, 4), dim3(512), 0, stream>>>(
        curm, G, Smir, BopO, Vn, states, obs);
}

// Round 12
// 827.966 us; speedup vs baseline: 1.1360x; 1.0482x over previous
//
#include <hip/hip_runtime.h>
#include <hip/hip_bf16.h>

// ---------------------------------------------------------------------------
// LinearSystem: chunked parallel scan (128 chunks x 8 steps), bf16 MFMA.
// Round 12 = R8 (best, 703us) with phase1's 7 sequential GEMM launches
// replaced by ONE persistent-block scan kernel (scan_k): each block owns 32
// (b,c) rows, keeps the running state in LDS, streams F through a
// double-buffered 128KB window. Power chain moved to 2 tiny aux launches +
// KS-round aux slices. Everything else identical to R8.
// ---------------------------------------------------------------------------

typedef short bfrag __attribute__((ext_vector_type(8)));   // 8 x bf16 bits
typedef float f32x4 __attribute__((ext_vector_type(4)));

__device__ __host__ inline unsigned short f2bf(float f) {
    union { float f; unsigned u; } x; x.f = f;
    unsigned r = x.u + 0x7fffu + ((x.u >> 16) & 1u);   // RNE
    return (unsigned short)(r >> 16);
}
__device__ inline float bf2f(unsigned short h) {
    union { unsigned u; float f; } x; x.u = ((unsigned)h) << 16;
    return x.f;
}

#define MSL 262144L   // 512*512 matrix stride

struct GemmDesc {
    const unsigned short* a0; const unsigned short* a1;  // A (k < ksplit -> a0)
    const unsigned short* b;                 // B, bf16, (N,K) row-major (B^T)
    float* c;                                // f32 C out (nullable)
    const unsigned short* cmbeta;            // bf16 beta source (beta==2)
    unsigned short* cm;                      // bf16 mirror out (nullable)
    unsigned short* cmT;                     // bf16 transposed mirror (512x512)
    long a0_base, a0_os, a0_is;              // row map: (r>>icl)*os + (r&mask)*is
    long a1_base, a1_os, a1_is;
    long a_zq, a_zr;
    long b_base, b_ldb, b_zq, b_zr;
    long c_base, c_os, c_is, c_zq, c_zr;
    long cm_base, cmb_base, cmT_base;
    long a_shift;                            // prefix rows (copy-only, acc=0)
    int a0_icl, a1_icl, c_icl, zdivl;
    int ksplit, K, beta;                     // beta: 0 none, 2 bf16 cmbeta
    int gxl, gyl, gz_main;
    // aux power-chain slice (bz >= gz_main): 512x512 C = xa[z] @ xb^T
    const unsigned short* xa; const unsigned short* xb;
    unsigned short* xcm; unsigned short* xcmT;
};

// 128x128 tile, BK=64, 4 waves (2x2 of 64x64), double-buffered 2-phase.
__global__ __launch_bounds__(256) void gemm_k(GemmDesc d) {
    __shared__ __align__(16) unsigned short As[2][128 * 64];
    __shared__ __align__(16) unsigned short Bs[2][128 * 64];
    const int tid  = threadIdx.x;
    const int lane = tid & 63;
    const int w    = tid >> 6;
    const int wrow = (w >> 1) * 64, wcol = (w & 1) * 64;

    // flattened grid + XCD-chunked bijective swizzle (x fastest)
    const unsigned nx = gridDim.x, ny = gridDim.y;
    const unsigned nwg = nx * ny * gridDim.z;
    unsigned wid = blockIdx.x + nx * (blockIdx.y + ny * blockIdx.z);
    if ((nwg & 7) == 0) wid = (wid & 7) * (nwg >> 3) + (wid >> 3);
    const int bx = wid & (nx - 1);
    const int by = (wid >> d.gxl) & (ny - 1);
    int bz = wid >> (d.gxl + d.gyl);

    if (bz >= d.gz_main) {                   // aux: 512x512 power-chain GEMM
        if (by >= 4) return;
        const long za = (long)(bz - d.gz_main) * MSL;
        d.a0 = d.xa; d.a0_base = za; d.a0_os = 512; d.a0_is = 0; d.a0_icl = 0;
        d.a1 = nullptr;
        d.b = d.xb; d.b_base = 0; d.b_ldb = 512; d.b_zq = d.b_zr = 0;
        d.K = 512; d.ksplit = 1 << 30; d.beta = 0; d.a_shift = 0;
        d.a_zq = d.a_zr = 0;
        d.c = nullptr; d.cm = d.xcm; d.cm_base = za;
        d.c_os = 512; d.c_is = 0; d.c_icl = 0; d.c_zq = d.c_zr = 0; d.c_base = 0;
        d.cmT = d.xcmT; d.cmT_base = za;
        bz = 0;
    }
    const long zq = (long)bz >> d.zdivl;
    const long zr = (long)bz & ((1L << d.zdivl) - 1);
    const int row0 = by * 128;
    const int col0 = bx * 128;

    const int g_r = tid >> 3;                // staging row within 32-row group
    const int g_k = (tid & 7) * 8;           // 16B k-slot
    const int swz = (g_r & 7) << 3;          // XOR swizzle (8-elem units)
    const long za_ = zq * d.a_zq + zr * d.a_zr;
    const long zb_ = zq * d.b_zq + zr * d.b_zr;

    const long m0a = (1L << d.a0_icl) - 1, m1a = (1L << d.a1_icl) - 1;
    long a0off[4], a1off[4], boff[4];
#pragma unroll
    for (int i = 0; i < 4; ++i) {
        long ar = (long)row0 + i * 32 + g_r - d.a_shift;
        if (ar < 0) ar = 0;
        a0off[i] = d.a0_base + za_ + (ar >> d.a0_icl) * d.a0_os + (ar & m0a) * d.a0_is;
        a1off[i] = d.a1 ? (d.a1_base + za_ + (ar >> d.a1_icl) * d.a1_os + (ar & m1a) * d.a1_is) : 0;
        boff[i]  = d.b_base + zb_ + (long)(col0 + i * 32 + g_r) * d.b_ldb;
    }

    bfrag ar_[4], br_[4];
    auto LOADT = [&](int t) {
        const int k0 = t * 64;
        const bool s1 = (k0 >= d.ksplit);
        const int kb = (s1 ? k0 - d.ksplit : k0) + g_k;
        const unsigned short* sp = s1 ? d.a1 : d.a0;
#pragma unroll
        for (int i = 0; i < 4; ++i)
            ar_[i] = *(const bfrag*)(sp + (s1 ? a1off[i] : a0off[i]) + kb);
#pragma unroll
        for (int i = 0; i < 4; ++i) br_[i] = *(const bfrag*)(d.b + boff[i] + k0 + g_k);
    };
    auto WRT = [&](int buf) {
#pragma unroll
        for (int i = 0; i < 4; ++i) {
            *(bfrag*)&As[buf][(i * 32 + g_r) * 64 + (g_k ^ swz)] = ar_[i];
            *(bfrag*)&Bs[buf][(i * 32 + g_r) * 64 + (g_k ^ swz)] = br_[i];
        }
    };

    f32x4 acc[4][4] = {};
    const int nt = d.K / 64;

    LOADT(0); WRT(0); __syncthreads();
    int cur = 0;
    for (int t = 0; t < nt; ++t) {
        if (t + 1 < nt) LOADT(t + 1);        // issue next-tile loads early
#pragma unroll
        for (int ks = 0; ks < 2; ++ks) {
            const int kk = ks * 32 + (lane >> 4) * 8;
            bfrag af[4], bf_[4];
#pragma unroll
            for (int mt = 0; mt < 4; ++mt) {
                const int r = wrow + mt * 16 + (lane & 15);
                af[mt] = *(const bfrag*)&As[cur][r * 64 + (kk ^ ((r & 7) << 3))];
            }
#pragma unroll
            for (int nn = 0; nn < 4; ++nn) {
                const int r = wcol + nn * 16 + (lane & 15);
                bf_[nn] = *(const bfrag*)&Bs[cur][r * 64 + (kk ^ ((r & 7) << 3))];
            }
#pragma unroll
            for (int mt = 0; mt < 4; ++mt)
#pragma unroll
                for (int nn = 0; nn < 4; ++nn)
                    acc[mt][nn] = __builtin_amdgcn_mfma_f32_16x16x32_bf16(
                        af[mt], bf_[nn], acc[mt][nn], 0, 0, 0);
        }
        if (t + 1 < nt) WRT(cur ^ 1);        // write-late (hidden under compute)
        __syncthreads();                     // ONE barrier per K-step
        cur ^= 1;
    }

    // ---- epilogue: C/D layout col=lane&15, row=(lane>>4)*4+j ----
    const long zc = zq * d.c_zq + zr * d.c_zr;
    const long mc = (1L << d.c_icl) - 1;
#pragma unroll
    for (int mt = 0; mt < 4; ++mt) {
        const int rb = row0 + wrow + mt * 16 + ((lane >> 4) << 2);
#pragma unroll
        for (int nn = 0; nn < 4; ++nn) {
            const int cc = col0 + wcol + nn * 16 + (lane & 15);
#pragma unroll
            for (int j = 0; j < 4; ++j) {
                const long r = rb + j;
                const long off = zc + (r >> d.c_icl) * d.c_os + (r & mc) * d.c_is + cc;
                float v = (r < d.a_shift) ? 0.0f : acc[mt][nn][j];
                if (d.beta == 2) v += bf2f(d.cmbeta[d.cmb_base + off]);
                if (d.c)  d.c[d.c_base + off] = v;
                if (d.cm) d.cm[d.cm_base + off] = f2bf(v);
                if (d.cmT) d.cmT[d.cmT_base + zc + (long)cc * 512 + r] = f2bf(v);
            }
        }
    }
}

// ---------------------------------------------------------------------------
// scan_k: full within-chunk scan in ONE launch. 256 blocks x 512 thr.
// Block owns rows rg0..rg0+31 of the (b,c) grid (b=rg>>7, c=rg&127); keeps the
// running 32x512 state in LDS (Scur); streams F via double-buffered 64KB
// slices. For t=1..7: Scur = Scur @ F^T + Smir[t]; write back to Smir[t].
// LDS: Scur 32KB + 2x64KB F buffers = 160KB exactly (1 block/CU).
// ---------------------------------------------------------------------------
__global__ __launch_bounds__(512) void scan_k(
        unsigned short* __restrict__ Smir, const unsigned short* __restrict__ Fm) {
    __shared__ __align__(16) unsigned char lds[163840];
    unsigned short* Scur = (unsigned short*)lds;           // [32][512] swizzled

    const int tid  = threadIdx.x;
    const int lane = tid & 63;
    const int w    = tid >> 6;               // 0..7 -> output cols w*64..
    const long rg0 = (long)blockIdx.x * 32;

    const int fr = tid >> 3;                 // F staging: row group 0..63
    const int fk = (tid & 7) * 8;            // 16B k-slot

    bfrag freg[8];
    auto LOADF = [&](int kt) {
#pragma unroll
        for (int i = 0; i < 8; ++i)
            freg[i] = *(const bfrag*)(Fm + (long)(fr + i * 64) * 512 + kt * 64 + fk);
    };
    auto WRTF = [&](int buf) {
        unsigned short* Fs = (unsigned short*)(lds + 32768 + buf * 65536);
#pragma unroll
        for (int i = 0; i < 8; ++i) {
            const int r = fr + i * 64;
            *(bfrag*)&Fs[r * 64 + (fk ^ ((r & 7) << 3))] = freg[i];
        }
    };

    // init: Scur = Smir[t=0] slice (32 rows x 512)
#pragma unroll
    for (int i = 0; i < 4; ++i) {
        const int fi = tid + i * 512;
        const int row = fi >> 6;
        const int col = (fi & 63) * 8;
        const long rg = rg0 + row;
        const long b = rg >> 7, c = rg & 127;
        bfrag v = *(const bfrag*)(Smir + b * 524288L + c * 4096L + col);
        *(bfrag*)&Scur[row * 512 + (col ^ ((row & 7) << 3))] = v;
    }
    LOADF(0); WRTF(0);
    __syncthreads();

    int cur = 0;
    for (int t = 1; t < 8; ++t) {
        f32x4 acc[2][4] = {};
        for (int kt = 0; kt < 8; ++kt) {
            const bool pre = !(t == 7 && kt == 7);
            if (pre) LOADF((kt + 1) & 7);    // prefetch next F slice (wraps to 0)
            const unsigned short* Fs = (const unsigned short*)(lds + 32768 + cur * 65536);
#pragma unroll
            for (int ks = 0; ks < 2; ++ks) {
                const int kk = ks * 32 + (lane >> 4) * 8;
                bfrag af[2], bf_[4];
#pragma unroll
                for (int mt = 0; mt < 2; ++mt) {
                    const int r = mt * 16 + (lane & 15);
                    const int col = kt * 64 + kk;
                    af[mt] = *(const bfrag*)&Scur[r * 512 + (col ^ ((r & 7) << 3))];
                }
#pragma unroll
                for (int nt = 0; nt < 4; ++nt) {
                    const int n = w * 64 + nt * 16 + (lane & 15);
                    bf_[nt] = *(const bfrag*)&Fs[n * 64 + (kk ^ ((n & 7) << 3))];
                }
#pragma unroll
                for (int mt = 0; mt < 2; ++mt)
#pragma unroll
                    for (int nt = 0; nt < 4; ++nt)
                        acc[mt][nt] = __builtin_amdgcn_mfma_f32_16x16x32_bf16(
                            af[mt], bf_[nt], acc[mt][nt], 0, 0, 0);
            }
            if (pre) WRTF(cur ^ 1);
            __syncthreads();
            cur ^= 1;
        }
        // epilogue: v = acc + u_t; write Smir[t] and update Scur
#pragma unroll
        for (int mt = 0; mt < 2; ++mt) {
#pragma unroll
            for (int nt = 0; nt < 4; ++nt) {
#pragma unroll
                for (int j = 0; j < 4; ++j) {
                    const int lr = mt * 16 + ((lane >> 4) << 2) + j;
                    const int cc = w * 64 + nt * 16 + (lane & 15);
                    const long rg = rg0 + lr;
                    const long b = rg >> 7, c = rg & 127;
                    const long off = b * 524288L + c * 4096L + (long)t * 512 + cc;
                    const unsigned short bv = f2bf(acc[mt][nt][j] + bf2f(Smir[off]));
                    Smir[off] = bv;
                    Scur[lr * 512 + (cc ^ ((lr & 7) << 3))] = bv;
                }
            }
        }
        __syncthreads();                     // Scur stable before next t
    }
}

// ---------------------------------------------------------------------------
// Fused phase3 + obs (R8 version). Grid (1, 64, 8).
// ---------------------------------------------------------------------------
__global__ __launch_bounds__(512) void p3obs_k(
        const unsigned short* __restrict__ carry, const unsigned short* __restrict__ Gm,
        const unsigned short* __restrict__ Smir, const unsigned short* __restrict__ BopO,
        const float* __restrict__ Vn, float* __restrict__ states, float* __restrict__ obs) {
    __shared__ __align__(16) unsigned char lds[163840];
    unsigned short* As1 = (unsigned short*)(lds);            // [128][64]  (phase A)
    unsigned short* Bs1 = (unsigned short*)(lds + 16384);    // [512][64]  (phase A)
    unsigned short* Sb  = (unsigned short*)(lds);            // [128][512] (phase B)
    unsigned short* A2  = (unsigned short*)(lds);            // [128][64]  (B2, over Sb)
    unsigned short* Ts  = (unsigned short*)(lds + 131072);   // [256][64]  (phase B)

    const int tid  = threadIdx.x;
    const int lane = tid & 63;
    const int w    = tid >> 6;               // 0..7
    const int wm   = w >> 2, wn = w & 3;     // 2 x 4 wave grid
    const int by   = blockIdx.y;             // 0..63
    const int k    = blockIdx.z;             // 0..7
    const unsigned short* G = Gm + (long)k * MSL;   // F^{k+1}

    f32x4 acc[4][8] = {};

    // ---------- GEMM1 ----------
    for (int kt = 0; kt < 8; ++kt) {
        __syncthreads();
#pragma unroll
        for (int i = 0; i < 2; ++i) {        // A tile: carry rows
            const int fi = tid + i * 512;
            const int row = fi >> 3, kk = (fi & 7) * 8;
            const long rg = (long)by * 128 + row;
            const long c = rg >> 6, b = rg & 63;
            bfrag v = *(const bfrag*)(carry + c * 32768 + b * 512 + kt * 64 + kk);
            *(bfrag*)&As1[row * 64 + (kk ^ ((row & 7) << 3))] = v;
        }
#pragma unroll
        for (int i = 0; i < 8; ++i) {        // B tile: G rows (all 512)
            const int fi = tid + i * 512;
            const int row = fi >> 3, kk = (fi & 7) * 8;
            bfrag v = *(const bfrag*)(G + (long)row * 512 + kt * 64 + kk);
            *(bfrag*)&Bs1[row * 64 + (kk ^ ((row & 7) << 3))] = v;
        }
        __syncthreads();
#pragma unroll
        for (int ks = 0; ks < 2; ++ks) {
            const int kk = ks * 32 + (lane >> 4) * 8;
            bfrag af[4], bf_[8];
#pragma unroll
            for (int mt = 0; mt < 4; ++mt) {
                const int r = wm * 64 + mt * 16 + (lane & 15);
                af[mt] = *(const bfrag*)&As1[r * 64 + (kk ^ ((r & 7) << 3))];
            }
#pragma unroll
            for (int nt = 0; nt < 8; ++nt) {
                const int n = wn * 128 + nt * 16 + (lane & 15);
                bf_[nt] = *(const bfrag*)&Bs1[n * 64 + (kk ^ ((n & 7) << 3))];
            }
#pragma unroll
            for (int mt = 0; mt < 4; ++mt)
#pragma unroll
                for (int nt = 0; nt < 8; ++nt)
                    acc[mt][nt] = __builtin_amdgcn_mfma_f32_16x16x32_bf16(
                        af[mt], bf_[nt], acc[mt][nt], 0, 0, 0);
        }
    }
    __syncthreads();

    // ---------- epilogue 1: +local, write states, build Sb ----------
#pragma unroll
    for (int mt = 0; mt < 4; ++mt) {
#pragma unroll
        for (int nt = 0; nt < 8; ++nt) {
#pragma unroll
            for (int j = 0; j < 4; ++j) {
                const int lr = wm * 64 + mt * 16 + ((lane >> 4) << 2) + j;
                const int cc = wn * 128 + nt * 16 + (lane & 15);
                const long rg = (long)by * 128 + lr;
                const long c = rg >> 6, b = rg & 63;
                const long t = c * 8 + k;
                float v = acc[mt][nt][j] + bf2f(Smir[b * 524288L + t * 512 + cc]);
                states[b * 524288L + t * 512 + cc] = v;
                Sb[lr * 512 + (cc ^ ((lr & 7) << 3))] = f2bf(v);
            }
        }
    }

    // ---------- GEMM2: obs = [Sb | cvt(Vn)] @ BopO^T ----------
    f32x4 acc2[4][4] = {};
    for (int kt = 0; kt < 12; ++kt) {
        __syncthreads();
#pragma unroll
        for (int i = 0; i < 4; ++i) {        // Ts: BopO rows 0..255
            const int fi = tid + i * 512;
            const int row = fi >> 3, kk = (fi & 7) * 8;
            bfrag v = *(const bfrag*)(BopO + (long)row * 768 + kt * 64 + kk);
            *(bfrag*)&Ts[row * 64 + (kk ^ ((row & 7) << 3))] = v;
        }
        if (kt >= 8) {
#pragma unroll
            for (int i = 0; i < 2; ++i) {    // A2: Vn f32 -> bf16
                const int fi = tid + i * 512;
                const int row = fi >> 3, kk = (fi & 7) * 8;
                const long rg = (long)by * 128 + row;
                const long c = rg >> 6, b = rg & 63;
                const long t = c * 8 + k;
                const float* p = Vn + b * 262144L + t * 256 + (kt - 8) * 64 + kk;
                f32x4 x0 = *(const f32x4*)p, x1 = *(const f32x4*)(p + 4);
                union { bfrag v; unsigned short h[8]; } u;
#pragma unroll
                for (int q = 0; q < 4; ++q) { u.h[q] = f2bf(x0[q]); u.h[4 + q] = f2bf(x1[q]); }
                *(bfrag*)&A2[row * 64 + (kk ^ ((row & 7) << 3))] = u.v;
            }
        }
        __syncthreads();
#pragma unroll
        for (int ks = 0; ks < 2; ++ks) {
            const int kk = ks * 32 + (lane >> 4) * 8;
            bfrag af[4], bf_[4];
#pragma unroll
            for (int mt = 0; mt < 4; ++mt) {
                const int r = wm * 64 + mt * 16 + (lane & 15);
                af[mt] = (kt < 8)
                    ? *(const bfrag*)&Sb[r * 512 + ((kt * 64 + kk) ^ ((r & 7) << 3))]
                    : *(const bfrag*)&A2[r * 64 + (kk ^ ((r & 7) << 3))];
            }
#pragma unroll
            for (int nt = 0; nt < 4; ++nt) {
                const int n = wn * 64 + nt * 16 + (lane & 15);
                bf_[nt] = *(const bfrag*)&Ts[n * 64 + (kk ^ ((n & 7) << 3))];
            }
#pragma unroll
            for (int mt = 0; mt < 4; ++mt)
#pragma unroll
                for (int nt = 0; nt < 4; ++nt)
                    acc2[mt][nt] = __builtin_amdgcn_mfma_f32_16x16x32_bf16(
                        af[mt], bf_[nt], acc2[mt][nt], 0, 0, 0);
        }
    }
    // ---------- epilogue 2: write obs ----------
#pragma unroll
    for (int mt = 0; mt < 4; ++mt) {
#pragma unroll
        for (int nt = 0; nt < 4; ++nt) {
#pragma unroll
            for (int j = 0; j < 4; ++j) {
                const int lr = wm * 64 + mt * 16 + ((lane >> 4) << 2) + j;
                const int cc = wn * 64 + nt * 16 + (lane & 15);
                const long rg = (long)by * 128 + lr;
                const long c = rg >> 6, b = rg & 63;
                const long t = c * 8 + k;
                obs[b * 262144L + t * 256 + cc] = acc2[mt][nt][j];
            }
        }
    }
}

// f32 -> bf16 bulk conversion, 8 elems/thread.
__global__ void cvt_k(const float* src, unsigned short* dst, long n) {
    long i = ((long)blockIdx.x * 256 + threadIdx.x) * 8;
    const long stride = (long)gridDim.x * 256 * 8;
    for (; i < n; i += stride) {
        f32x4 x0 = *(const f32x4*)(src + i), x1 = *(const f32x4*)(src + i + 4);
        union { bfrag v; unsigned short h[8]; } t;
#pragma unroll
        for (int q = 0; q < 4; ++q) { t.h[q] = f2bf(x0[q]); t.h[4 + q] = f2bf(x1[q]); }
        *(bfrag*)(dst + i) = t.v;
    }
}

// Build bf16 operators: BopD (512x768)=[B_mat|sqrt_S_W], BopO (256x768)=[H|sqrt_S_V],
// G[0]=F, Gt[0]=F^T.
__global__ void build_ops_k(const float* F, const float* Bm, const float* H,
                            const float* sW, const float* sV,
                            unsigned short* bopd, unsigned short* bopo,
                            unsigned short* G1, unsigned short* Gt1) {
    int i = blockIdx.x * 256 + threadIdx.x;
    const int n1 = 512 * 768, n2 = 256 * 768, n3 = 512 * 512;
    if (i < n1) { int n = i / 768, k = i % 768;
        bopd[i] = f2bf(k < 256 ? Bm[n * 256 + k] : sW[n * 512 + (k - 256)]); return; }
    i -= n1;
    if (i < n2) { int o = i / 768, k = i % 768;
        bopo[i] = f2bf(k < 512 ? H[o * 512 + k] : sV[o * 256 + (k - 512)]); return; }
    i -= n2;
    if (i < n3) { G1[i] = f2bf(F[i]); return; }
    i -= n3;
    if (i < n3) { int r = i / 512, c = i % 512; Gt1[i] = f2bf(F[c * 512 + r]); }
}

// Initial carries: dst[c*32768 + b*512 + s]; c==0 from st0 (f32), else from
// Smir local[c-1, 7] = Smir[b*524288 + (c-1)*4096 + 3584 + s].
__global__ void init_carry_k(const float* st0, const unsigned short* Smir,
                             unsigned short* dst) {
    const long i8 = ((long)blockIdx.x * 256 + threadIdx.x) * 8;  // 4,194,304 total
    if (i8 >= 4194304L) return;
    const long c = i8 >> 15, rem = i8 & 32767L;
    const long b = rem >> 9, s = rem & 511L;
    union { bfrag v; unsigned short h[8]; } t;
    if (c == 0) {
        const float* p = st0 + b * 512 + s;
        f32x4 x0 = *(const f32x4*)p, x1 = *(const f32x4*)(p + 4);
#pragma unroll
        for (int q = 0; q < 4; ++q) { t.h[q] = f2bf(x0[q]); t.h[4 + q] = f2bf(x1[q]); }
    } else {
        t.v = *(const bfrag*)(Smir + b * 524288L + (c - 1) * 4096L + 3584L + s);
    }
    *(bfrag*)(dst + i8) = t.v;
}

static GemmDesc D0() {
    GemmDesc d = {};
    d.zdivl = 30;
    d.ksplit = 1 << 30;
    d.b_ldb = 512; d.K = 512;
    d.gz_main = 1 << 30;
    return d;
}

extern "C" void kernel_launch(void* const* d_in, const int* in_sizes, int n_in,
                              void* d_out, int out_size, void* d_ws, size_t ws_size,
                              hipStream_t stream) {
    const float* st0 = (const float*)d_in[0];
    const float* inp = (const float*)d_in[1];
    const float* Wn  = (const float*)d_in[2];
    const float* Vn  = (const float*)d_in[3];
    const float* F   = (const float*)d_in[4];
    const float* Bm  = (const float*)d_in[5];
    const float* H   = (const float*)d_in[6];
    const float* sW  = (const float*)d_in[7];
    const float* sV  = (const float*)d_in[8];

    float* states = (float*)d_out;              // (64,1024,512) f32
    float* obs    = states + 33554432L;         // (64,1024,256) f32

    const long MS = MSL;
    const long CB = 32768;    // 64*512 per-chunk carry block
    const int  NC = 128;      // chunks

    // d_out states region: inp/Wn bf16 scratch (dead after drive).
    unsigned short* inpb = (unsigned short*)states;
    unsigned short* Wnb  = inpb + 16777216L;

    // ws layout (all bf16 bits) — identical to R8
    unsigned short* Smir = (unsigned short*)d_ws;          // 33,554,432
    unsigned short* G    = Smir + 33554432L;               // G[j]=F^{j+1}, j=0..7
    unsigned short* Gt   = G + 8 * MS;
    unsigned short* Qb   = Gt + 8 * MS;                    // F^{16*2^j}, j=0..5
    unsigned short* Qtb  = Qb + 6 * MS;                    // j=0..4 (+1 spare)
    unsigned short* BopD = Qtb + 6 * MS;                   // 512*768
    unsigned short* BopO = BopD + 512 * 768;               // 256*768
    unsigned short* a0m  = BopO + 256 * 768;               // NC*CB carries
    unsigned short* a1m  = a0m + (long)NC * CB;
    (void)in_sizes; (void)n_in; (void)out_size; (void)ws_size;

    auto L = [&](const GemmDesc& d, int gx, int gxl, int gy, int gyl, int gz) {
        GemmDesc dd = d; dd.gxl = gxl; dd.gyl = gyl;
        gemm_k<<<dim3(gx, gy, gz), dim3(256), 0, stream>>>(dd);
    };

    // 0) bf16 prepass: inp, Wn -> d_out scratch
    cvt_k<<<dim3(2048), dim3(256), 0, stream>>>(inp, inpb, 16777216L);
    cvt_k<<<dim3(2048), dim3(256), 0, stream>>>(Wn, Wnb, 33554432L);

    // 1) operators + F, F^T
    build_ops_k<<<dim3(4352), dim3(256), 0, stream>>>(F, Bm, H, sW, sV, BopD, BopO, G, Gt);

    // 2) drive = [inputs | W_noise] @ BopD^T -> Smir ; aux: F^2 (+T)
    {
        GemmDesc d = D0();
        d.a0 = inpb; d.a0_os = 256;
        d.a1 = Wnb;  d.a1_os = 512;
        d.ksplit = 256; d.K = 768;
        d.b = BopD; d.b_ldb = 768;
        d.cm = Smir; d.c_os = 512;
        d.gz_main = 1;
        d.xa = G; d.xb = Gt; d.xcm = G + MS; d.xcmT = Gt + MS;
        L(d, 4, 2, 512, 9, 2);
    }

    // 3a) aux-only: F^3 = F@F^2, F^4 = F^2@F^2 -> G[2],G[3] (+T)
    {
        GemmDesc d = D0();
        d.gz_main = 0;
        d.xa = G; d.xb = Gt + MS; d.xcm = G + 2 * MS; d.xcmT = Gt + 2 * MS;
        L(d, 4, 2, 4, 2, 2);
    }
    // 3b) aux-only: F^5..F^8 = {F,F^2,F^3,F^4}@F^4 -> G[4..7] (+T)
    {
        GemmDesc d = D0();
        d.gz_main = 0;
        d.xa = G; d.xb = Gt + 3 * MS; d.xcm = G + 4 * MS; d.xcmT = Gt + 4 * MS;
        L(d, 4, 2, 4, 2, 4);
    }

    // 4) phase 1 in ONE launch: per-block local scan over t=1..7
    scan_k<<<dim3(256), dim3(512), 0, stream>>>(Smir, G);

    // 5) initial carries
    init_carry_k<<<dim3(2048), dim3(256), 0, stream>>>(st0, Smir, a0m);

    // 6) Kogge-Stone over chunks (7 rounds); aux at round ri computes Qb[ri]
    //    (F^{16*2^ri}) used by round s=2^{ri+1}.
    unsigned short* curm = a0m;
    unsigned short* nxtm = a1m;
    int ri = 0;
    for (int s = 1; s < NC; s <<= 1, ++ri) {
        GemmDesc d = D0();
        d.a0 = curm; d.a0_os = 512;
        d.a_shift = (long)s * 64;
        if (s == 1) { d.b = G + 7 * MS; }                                // F^8
        else        { d.b = Qb + (long)(__builtin_ctz(s) - 1) * MS; }    // F^{8s}
        d.beta = 2; d.cmbeta = curm; d.cmb_base = 0;
        d.cm = nxtm; d.c_os = 512;
        int n = 0;
        if (ri < 6) {                        // aux: Qb[ri] = (ri? Qb[ri-1] : G7)^2
            d.gz_main = 1;
            d.xa = ri ? (Qb + (long)(ri - 1) * MS) : (G + 7 * MS);
            d.xb = ri ? (Qtb + (long)(ri - 1) * MS) : (Gt + 7 * MS);
            d.xcm = Qb + (long)ri * MS;
            d.xcmT = (ri < 5) ? (Qtb + (long)ri * MS) : nullptr;
            n = 1;
        }
        L(d, 4, 2, 64, 6, 1 + n);
        unsigned short* tm = curm; curm = nxtm; nxtm = tm;
    }
    // after 7 rounds: curm = a1m

    // 7) fused phase3 + obs
    p3obs_k<<<dim3(1, 64, 8), dim3(512), 0, stream>>>(
        curm, G, Smir, BopO, Vn, states, obs);
}

// Round 13
// 778.066 us; speedup vs baseline: 1.2089x; 1.0641x over previous
//
#include <hip/hip_runtime.h>
#include <hip/hip_bf16.h>

// ---------------------------------------------------------------------------
// LinearSystem: chunked parallel scan (128 chunks x 8 steps), bf16 MFMA.
// Round 13 = R8 (best, 703us) verbatim with ONE change: p3obs_k GEMM1 is
// double-buffered (issue-early/write-late, one barrier per kt), grid kept at
// (1,64,8) so the R8 G/Smir locality (FETCH ~93MB) is preserved.
// ---------------------------------------------------------------------------

typedef short bfrag __attribute__((ext_vector_type(8)));   // 8 x bf16 bits
typedef float f32x4 __attribute__((ext_vector_type(4)));

__device__ __host__ inline unsigned short f2bf(float f) {
    union { float f; unsigned u; } x; x.f = f;
    unsigned r = x.u + 0x7fffu + ((x.u >> 16) & 1u);   // RNE
    return (unsigned short)(r >> 16);
}
__device__ inline float bf2f(unsigned short h) {
    union { unsigned u; float f; } x; x.u = ((unsigned)h) << 16;
    return x.f;
}

#define MSL 262144L   // 512*512 matrix stride

struct GemmDesc {
    const unsigned short* a0; const unsigned short* a1;  // A (k < ksplit -> a0)
    const unsigned short* b;                 // B, bf16, (N,K) row-major (B^T)
    float* c;                                // f32 C out (nullable)
    const unsigned short* cmbeta;            // bf16 beta source (beta==2)
    unsigned short* cm;                      // bf16 mirror out (nullable)
    unsigned short* cmT;                     // bf16 transposed mirror (512x512)
    long a0_base, a0_os, a0_is;              // row map: (r>>icl)*os + (r&mask)*is
    long a1_base, a1_os, a1_is;
    long a_zq, a_zr;
    long b_base, b_ldb, b_zq, b_zr;
    long c_base, c_os, c_is, c_zq, c_zr;
    long cm_base, cmb_base, cmT_base;
    long a_shift;                            // prefix rows (copy-only, acc=0)
    int a0_icl, a1_icl, c_icl, zdivl;
    int ksplit, K, beta;                     // beta: 0 none, 2 bf16 cmbeta
    int gxl, gyl, gz_main;
    // aux power-chain slice (bz >= gz_main): 512x512 C = xa[z] @ xb^T
    const unsigned short* xa; const unsigned short* xb;
    unsigned short* xcm; unsigned short* xcmT;
};

// 128x128 tile, BK=64, 4 waves (2x2 of 64x64), double-buffered 2-phase.
__global__ __launch_bounds__(256) void gemm_k(GemmDesc d) {
    __shared__ __align__(16) unsigned short As[2][128 * 64];
    __shared__ __align__(16) unsigned short Bs[2][128 * 64];
    const int tid  = threadIdx.x;
    const int lane = tid & 63;
    const int w    = tid >> 6;
    const int wrow = (w >> 1) * 64, wcol = (w & 1) * 64;

    // flattened grid + XCD-chunked bijective swizzle (x fastest)
    const unsigned nx = gridDim.x, ny = gridDim.y;
    const unsigned nwg = nx * ny * gridDim.z;
    unsigned wid = blockIdx.x + nx * (blockIdx.y + ny * blockIdx.z);
    if ((nwg & 7) == 0) wid = (wid & 7) * (nwg >> 3) + (wid >> 3);
    const int bx = wid & (nx - 1);
    const int by = (wid >> d.gxl) & (ny - 1);
    int bz = wid >> (d.gxl + d.gyl);

    if (bz >= d.gz_main) {                   // aux: 512x512 power-chain GEMM
        if (by >= 4) return;
        const long za = (long)(bz - d.gz_main) * MSL;
        d.a0 = d.xa; d.a0_base = za; d.a0_os = 512; d.a0_is = 0; d.a0_icl = 0;
        d.a1 = nullptr;
        d.b = d.xb; d.b_base = 0; d.b_ldb = 512; d.b_zq = d.b_zr = 0;
        d.K = 512; d.ksplit = 1 << 30; d.beta = 0; d.a_shift = 0;
        d.a_zq = d.a_zr = 0;
        d.c = nullptr; d.cm = d.xcm; d.cm_base = za;
        d.c_os = 512; d.c_is = 0; d.c_icl = 0; d.c_zq = d.c_zr = 0; d.c_base = 0;
        d.cmT = d.xcmT; d.cmT_base = za;
        bz = 0;
    }
    const long zq = (long)bz >> d.zdivl;
    const long zr = (long)bz & ((1L << d.zdivl) - 1);
    const int row0 = by * 128;
    const int col0 = bx * 128;

    const int g_r = tid >> 3;                // staging row within 32-row group
    const int g_k = (tid & 7) * 8;           // 16B k-slot
    const int swz = (g_r & 7) << 3;          // XOR swizzle (8-elem units)
    const long za_ = zq * d.a_zq + zr * d.a_zr;
    const long zb_ = zq * d.b_zq + zr * d.b_zr;

    const long m0a = (1L << d.a0_icl) - 1, m1a = (1L << d.a1_icl) - 1;
    long a0off[4], a1off[4], boff[4];
#pragma unroll
    for (int i = 0; i < 4; ++i) {
        long ar = (long)row0 + i * 32 + g_r - d.a_shift;
        if (ar < 0) ar = 0;
        a0off[i] = d.a0_base + za_ + (ar >> d.a0_icl) * d.a0_os + (ar & m0a) * d.a0_is;
        a1off[i] = d.a1 ? (d.a1_base + za_ + (ar >> d.a1_icl) * d.a1_os + (ar & m1a) * d.a1_is) : 0;
        boff[i]  = d.b_base + zb_ + (long)(col0 + i * 32 + g_r) * d.b_ldb;
    }

    bfrag ar_[4], br_[4];
    auto LOADT = [&](int t) {
        const int k0 = t * 64;
        const bool s1 = (k0 >= d.ksplit);
        const int kb = (s1 ? k0 - d.ksplit : k0) + g_k;
        const unsigned short* sp = s1 ? d.a1 : d.a0;
#pragma unroll
        for (int i = 0; i < 4; ++i)
            ar_[i] = *(const bfrag*)(sp + (s1 ? a1off[i] : a0off[i]) + kb);
#pragma unroll
        for (int i = 0; i < 4; ++i) br_[i] = *(const bfrag*)(d.b + boff[i] + k0 + g_k);
    };
    auto WRT = [&](int buf) {
#pragma unroll
        for (int i = 0; i < 4; ++i) {
            *(bfrag*)&As[buf][(i * 32 + g_r) * 64 + (g_k ^ swz)] = ar_[i];
            *(bfrag*)&Bs[buf][(i * 32 + g_r) * 64 + (g_k ^ swz)] = br_[i];
        }
    };

    f32x4 acc[4][4] = {};
    const int nt = d.K / 64;

    LOADT(0); WRT(0); __syncthreads();
    int cur = 0;
    for (int t = 0; t < nt; ++t) {
        if (t + 1 < nt) LOADT(t + 1);        // issue next-tile loads early
#pragma unroll
        for (int ks = 0; ks < 2; ++ks) {
            const int kk = ks * 32 + (lane >> 4) * 8;
            bfrag af[4], bf_[4];
#pragma unroll
            for (int mt = 0; mt < 4; ++mt) {
                const int r = wrow + mt * 16 + (lane & 15);
                af[mt] = *(const bfrag*)&As[cur][r * 64 + (kk ^ ((r & 7) << 3))];
            }
#pragma unroll
            for (int nn = 0; nn < 4; ++nn) {
                const int r = wcol + nn * 16 + (lane & 15);
                bf_[nn] = *(const bfrag*)&Bs[cur][r * 64 + (kk ^ ((r & 7) << 3))];
            }
#pragma unroll
            for (int mt = 0; mt < 4; ++mt)
#pragma unroll
                for (int nn = 0; nn < 4; ++nn)
                    acc[mt][nn] = __builtin_amdgcn_mfma_f32_16x16x32_bf16(
                        af[mt], bf_[nn], acc[mt][nn], 0, 0, 0);
        }
        if (t + 1 < nt) WRT(cur ^ 1);        // write-late (hidden under compute)
        __syncthreads();                     // ONE barrier per K-step
        cur ^= 1;
    }

    // ---- epilogue: C/D layout col=lane&15, row=(lane>>4)*4+j ----
    const long zc = zq * d.c_zq + zr * d.c_zr;
    const long mc = (1L << d.c_icl) - 1;
#pragma unroll
    for (int mt = 0; mt < 4; ++mt) {
        const int rb = row0 + wrow + mt * 16 + ((lane >> 4) << 2);
#pragma unroll
        for (int nn = 0; nn < 4; ++nn) {
            const int cc = col0 + wcol + nn * 16 + (lane & 15);
#pragma unroll
            for (int j = 0; j < 4; ++j) {
                const long r = rb + j;
                const long off = zc + (r >> d.c_icl) * d.c_os + (r & mc) * d.c_is + cc;
                float v = (r < d.a_shift) ? 0.0f : acc[mt][nn][j];
                if (d.beta == 2) v += bf2f(d.cmbeta[d.cmb_base + off]);
                if (d.c)  d.c[d.c_base + off] = v;
                if (d.cm) d.cm[d.cm_base + off] = f2bf(v);
                if (d.cmT) d.cmT[d.cmT_base + zc + (long)cc * 512 + r] = f2bf(v);
            }
        }
    }
}

// ---------------------------------------------------------------------------
// Fused phase3 + obs. Grid (1, 64, 8) — z = k slowest (R8 locality).
// 512 threads, 160 KiB LDS.
//   GEMM1 (double-buffered): s[128x512] = carry @ (F^{k+1})^T; +local,
//          write states f32, deposit bf16 rows into LDS Sb.
//   GEMM2: obs[128x256] = [Sb | cvt(Vn)] @ BopO^T; write obs f32.
// LDS map: GEMM1 phase: Bs1[buf] at 0/65536 (64KB ea), As1[buf] at
// 131072/147456 (16KB ea). Post-GEMM1: Sb at 0 (128KB), Ts at 131072 (32KB),
// A2 overlays Sb (kt>=8).
// ---------------------------------------------------------------------------
__global__ __launch_bounds__(512) void p3obs_k(
        const unsigned short* __restrict__ carry, const unsigned short* __restrict__ Gm,
        const unsigned short* __restrict__ Smir, const unsigned short* __restrict__ BopO,
        const float* __restrict__ Vn, float* __restrict__ states, float* __restrict__ obs) {
    __shared__ __align__(16) unsigned char lds[163840];
    unsigned short* Sb = (unsigned short*)lds;             // [128][512] post-GEMM1
    unsigned short* Ts = (unsigned short*)(lds + 131072);  // [256][64]
    unsigned short* A2 = (unsigned short*)lds;             // [128][64] (kt>=8)

    const int tid  = threadIdx.x;
    const int lane = tid & 63;
    const int w    = tid >> 6;               // 0..7
    const int wm   = w >> 2, wn = w & 3;     // 2 x 4 wave grid
    const int by   = blockIdx.y;             // 0..63
    const int k    = blockIdx.z;             // 0..7
    const unsigned short* G = Gm + (long)k * MSL;   // F^{k+1}

    const int srow = tid >> 3;               // 0..63
    const int skk  = (tid & 7) * 8;

    bfrag areg[2], breg[8];
    auto LOADT = [&](int kt) {
#pragma unroll
        for (int i = 0; i < 2; ++i) {
            const int row = srow + i * 64;
            const long rg = (long)by * 128 + row;
            areg[i] = *(const bfrag*)(carry + (rg >> 6) * 32768 + (rg & 63) * 512 + kt * 64 + skk);
        }
#pragma unroll
        for (int i = 0; i < 8; ++i)
            breg[i] = *(const bfrag*)(G + (long)(srow + i * 64) * 512 + kt * 64 + skk);
    };
    auto WRT = [&](int buf) {
        unsigned short* as = (unsigned short*)(lds + 131072 + buf * 16384);
        unsigned short* bs = (unsigned short*)(lds + buf * 65536);
#pragma unroll
        for (int i = 0; i < 2; ++i) {
            const int r = srow + i * 64;
            *(bfrag*)&as[r * 64 + (skk ^ ((r & 7) << 3))] = areg[i];
        }
#pragma unroll
        for (int i = 0; i < 8; ++i) {
            const int r = srow + i * 64;
            *(bfrag*)&bs[r * 64 + (skk ^ ((r & 7) << 3))] = breg[i];
        }
    };

    // ---------- GEMM1 (pipelined: issue-early / write-late) ----------
    f32x4 acc[4][8] = {};
    LOADT(0); WRT(0); __syncthreads();
    int cur = 0;
    for (int kt = 0; kt < 8; ++kt) {
        if (kt < 7) LOADT(kt + 1);
        const unsigned short* as = (const unsigned short*)(lds + 131072 + cur * 16384);
        const unsigned short* bs = (const unsigned short*)(lds + cur * 65536);
#pragma unroll
        for (int ks = 0; ks < 2; ++ks) {
            const int kk = ks * 32 + (lane >> 4) * 8;
            bfrag af[4], bf_[8];
#pragma unroll
            for (int mt = 0; mt < 4; ++mt) {
                const int r = wm * 64 + mt * 16 + (lane & 15);
                af[mt] = *(const bfrag*)&as[r * 64 + (kk ^ ((r & 7) << 3))];
            }
#pragma unroll
            for (int nt = 0; nt < 8; ++nt) {
                const int n = wn * 128 + nt * 16 + (lane & 15);
                bf_[nt] = *(const bfrag*)&bs[n * 64 + (kk ^ ((n & 7) << 3))];
            }
#pragma unroll
            for (int mt = 0; mt < 4; ++mt)
#pragma unroll
                for (int nt = 0; nt < 8; ++nt)
                    acc[mt][nt] = __builtin_amdgcn_mfma_f32_16x16x32_bf16(
                        af[mt], bf_[nt], acc[mt][nt], 0, 0, 0);
        }
        if (kt < 7) WRT(cur ^ 1);            // write-late (vmcnt hidden here)
        __syncthreads();                     // ONE barrier per kt
        cur ^= 1;
    }

    // ---------- epilogue 1: +local, write states, build Sb ----------
#pragma unroll
    for (int mt = 0; mt < 4; ++mt) {
#pragma unroll
        for (int nt = 0; nt < 8; ++nt) {
#pragma unroll
            for (int j = 0; j < 4; ++j) {
                const int lr = wm * 64 + mt * 16 + ((lane >> 4) << 2) + j;
                const int cc = wn * 128 + nt * 16 + (lane & 15);
                const long rg = (long)by * 128 + lr;
                const long c = rg >> 6, b = rg & 63;
                const long t = c * 8 + k;
                float v = acc[mt][nt][j] + bf2f(Smir[b * 524288L + t * 512 + cc]);
                states[b * 524288L + t * 512 + cc] = v;
                Sb[lr * 512 + (cc ^ ((lr & 7) << 3))] = f2bf(v);
            }
        }
    }

    // ---------- GEMM2: obs = [Sb | cvt(Vn)] @ BopO^T ----------
    f32x4 acc2[4][4] = {};
    for (int kt = 0; kt < 12; ++kt) {
        __syncthreads();
#pragma unroll
        for (int i = 0; i < 4; ++i) {        // Ts: BopO rows 0..255
            const int fi = tid + i * 512;
            const int row = fi >> 3, kk = (fi & 7) * 8;
            bfrag v = *(const bfrag*)(BopO + (long)row * 768 + kt * 64 + kk);
            *(bfrag*)&Ts[row * 64 + (kk ^ ((row & 7) << 3))] = v;
        }
        if (kt >= 8) {
#pragma unroll
            for (int i = 0; i < 2; ++i) {    // A2: Vn f32 -> bf16
                const int fi = tid + i * 512;
                const int row = fi >> 3, kk = (fi & 7) * 8;
                const long rg = (long)by * 128 + row;
                const long c = rg >> 6, b = rg & 63;
                const long t = c * 8 + k;
                const float* p = Vn + b * 262144L + t * 256 + (kt - 8) * 64 + kk;
                f32x4 x0 = *(const f32x4*)p, x1 = *(const f32x4*)(p + 4);
                union { bfrag v; unsigned short h[8]; } u;
#pragma unroll
                for (int q = 0; q < 4; ++q) { u.h[q] = f2bf(x0[q]); u.h[4 + q] = f2bf(x1[q]); }
                *(bfrag*)&A2[row * 64 + (kk ^ ((row & 7) << 3))] = u.v;
            }
        }
        __syncthreads();
#pragma unroll
        for (int ks = 0; ks < 2; ++ks) {
            const int kk = ks * 32 + (lane >> 4) * 8;
            bfrag af[4], bf_[4];
#pragma unroll
            for (int mt = 0; mt < 4; ++mt) {
                const int r = wm * 64 + mt * 16 + (lane & 15);
                af[mt] = (kt < 8)
                    ? *(const bfrag*)&Sb[r * 512 + ((kt * 64 + kk) ^ ((r & 7) << 3))]
                    : *(const bfrag*)&A2[r * 64 + (kk ^ ((r & 7) << 3))];
            }
#pragma unroll
            for (int nt = 0; nt < 4; ++nt) {
                const int n = wn * 64 + nt * 16 + (lane & 15);
                bf_[nt] = *(const bfrag*)&Ts[n * 64 + (kk ^ ((n & 7) << 3))];
            }
#pragma unroll
            for (int mt = 0; mt < 4; ++mt)
#pragma unroll
                for (int nt = 0; nt < 4; ++nt)
                    acc2[mt][nt] = __builtin_amdgcn_mfma_f32_16x16x32_bf16(
                        af[mt], bf_[nt], acc2[mt][nt], 0, 0, 0);
        }
    }
    // ---------- epilogue 2: write obs ----------
#pragma unroll
    for (int mt = 0; mt < 4; ++mt) {
#pragma unroll
        for (int nt = 0; nt < 4; ++nt) {
#pragma unroll
            for (int j = 0; j < 4; ++j) {
                const int lr = wm * 64 + mt * 16 + ((lane >> 4) << 2) + j;
                const int cc = wn * 64 + nt * 16 + (lane & 15);
                const long rg = (long)by * 128 + lr;
                const long c = rg >> 6, b = rg & 63;
                const long t = c * 8 + k;
                obs[b * 262144L + t * 256 + cc] = acc2[mt][nt][j];
            }
        }
    }
}

// f32 -> bf16 bulk conversion, 8 elems/thread.
__global__ void cvt_k(const float* src, unsigned short* dst, long n) {
    long i = ((long)blockIdx.x * 256 + threadIdx.x) * 8;
    const long stride = (long)gridDim.x * 256 * 8;
    for (; i < n; i += stride) {
        f32x4 x0 = *(const f32x4*)(src + i), x1 = *(const f32x4*)(src + i + 4);
        union { bfrag v; unsigned short h[8]; } t;
#pragma unroll
        for (int q = 0; q < 4; ++q) { t.h[q] = f2bf(x0[q]); t.h[4 + q] = f2bf(x1[q]); }
        *(bfrag*)(dst + i) = t.v;
    }
}

// Build bf16 operators: BopD (512x768)=[B_mat|sqrt_S_W], BopO (256x768)=[H|sqrt_S_V],
// G[0]=F, Gt[0]=F^T.
__global__ void build_ops_k(const float* F, const float* Bm, const float* H,
                            const float* sW, const float* sV,
                            unsigned short* bopd, unsigned short* bopo,
                            unsigned short* G1, unsigned short* Gt1) {
    int i = blockIdx.x * 256 + threadIdx.x;
    const int n1 = 512 * 768, n2 = 256 * 768, n3 = 512 * 512;
    if (i < n1) { int n = i / 768, k = i % 768;
        bopd[i] = f2bf(k < 256 ? Bm[n * 256 + k] : sW[n * 512 + (k - 256)]); return; }
    i -= n1;
    if (i < n2) { int o = i / 768, k = i % 768;
        bopo[i] = f2bf(k < 512 ? H[o * 512 + k] : sV[o * 256 + (k - 512)]); return; }
    i -= n2;
    if (i < n3) { G1[i] = f2bf(F[i]); return; }
    i -= n3;
    if (i < n3) { int r = i / 512, c = i % 512; Gt1[i] = f2bf(F[c * 512 + r]); }
}

// Initial carries: dst[c*32768 + b*512 + s]; c==0 from st0 (f32), else from
// Smir local[c-1, 7] = Smir[b*524288 + (c-1)*4096 + 3584 + s].
__global__ void init_carry_k(const float* st0, const unsigned short* Smir,
                             unsigned short* dst) {
    const long i8 = ((long)blockIdx.x * 256 + threadIdx.x) * 8;  // 4,194,304 total
    if (i8 >= 4194304L) return;
    const long c = i8 >> 15, rem = i8 & 32767L;
    const long b = rem >> 9, s = rem & 511L;
    union { bfrag v; unsigned short h[8]; } t;
    if (c == 0) {
        const float* p = st0 + b * 512 + s;
        f32x4 x0 = *(const f32x4*)p, x1 = *(const f32x4*)(p + 4);
#pragma unroll
        for (int q = 0; q < 4; ++q) { t.h[q] = f2bf(x0[q]); t.h[4 + q] = f2bf(x1[q]); }
    } else {
        t.v = *(const bfrag*)(Smir + b * 524288L + (c - 1) * 4096L + 3584L + s);
    }
    *(bfrag*)(dst + i8) = t.v;
}

static GemmDesc D0() {
    GemmDesc d = {};
    d.zdivl = 30;
    d.ksplit = 1 << 30;
    d.b_ldb = 512; d.K = 512;
    d.gz_main = 1 << 30;
    return d;
}

extern "C" void kernel_launch(void* const* d_in, const int* in_sizes, int n_in,
                              void* d_out, int out_size, void* d_ws, size_t ws_size,
                              hipStream_t stream) {
    const float* st0 = (const float*)d_in[0];
    const float* inp = (const float*)d_in[1];
    const float* Wn  = (const float*)d_in[2];
    const float* Vn  = (const float*)d_in[3];
    const float* F   = (const float*)d_in[4];
    const float* Bm  = (const float*)d_in[5];
    const float* H   = (const float*)d_in[6];
    const float* sW  = (const float*)d_in[7];
    const float* sV  = (const float*)d_in[8];

    float* states = (float*)d_out;              // (64,1024,512) f32
    float* obs    = states + 33554432L;         // (64,1024,256) f32

    const long MS = MSL;
    const long CB = 32768;    // 64*512 per-chunk carry block
    const int  NC = 128;      // chunks
    const int  CL = 8;        // chunk length
    const long TOS = 524288;  // batch stride (1024*512)
    const long COS = (long)CL * 512;   // chunk stride = 4096

    // d_out states region: inp/Wn bf16 scratch (dead after drive; p3obs writes
    // states only at the very end).
    unsigned short* inpb = (unsigned short*)states;
    unsigned short* Wnb  = inpb + 16777216L;

    // ws layout (all bf16 bits) — identical to R8
    unsigned short* Smir = (unsigned short*)d_ws;          // 33,554,432
    unsigned short* G    = Smir + 33554432L;               // G[j]=F^{j+1}, j=0..7
    unsigned short* Gt   = G + 8 * MS;
    unsigned short* Qb   = Gt + 8 * MS;                    // F^{16*2^j}, j=0..5
    unsigned short* Qtb  = Qb + 6 * MS;                    // j=0..4 (+1 spare)
    unsigned short* BopD = Qtb + 6 * MS;                   // 512*768
    unsigned short* BopO = BopD + 512 * 768;               // 256*768
    unsigned short* a0m  = BopO + 256 * 768;               // NC*CB carries
    unsigned short* a1m  = a0m + (long)NC * CB;
    (void)in_sizes; (void)n_in; (void)out_size; (void)ws_size;

    auto L = [&](const GemmDesc& d, int gx, int gxl, int gy, int gyl, int gz) {
        GemmDesc dd = d; dd.gxl = gxl; dd.gyl = gyl;
        gemm_k<<<dim3(gx, gy, gz), dim3(256), 0, stream>>>(dd);
    };

    // 0) bf16 prepass: inp, Wn -> d_out scratch
    cvt_k<<<dim3(2048), dim3(256), 0, stream>>>(inp, inpb, 16777216L);
    cvt_k<<<dim3(2048), dim3(256), 0, stream>>>(Wn, Wnb, 33554432L);

    // 1) operators + F, F^T
    build_ops_k<<<dim3(4352), dim3(256), 0, stream>>>(F, Bm, H, sW, sV, BopD, BopO, G, Gt);

    // 2) drive = [inputs | W_noise] @ BopD^T -> Smir (all-bf16)
    {
        GemmDesc d = D0();
        d.a0 = inpb; d.a0_os = 256;
        d.a1 = Wnb;  d.a1_os = 512;
        d.ksplit = 256; d.K = 768;
        d.b = BopD; d.b_ldb = 768;
        d.cm = Smir; d.c_os = 512;
        L(d, 4, 2, 512, 9, 1);
    }

    // 3) phase 1 (7 sequential steps) with fused power-chain aux slices
    //    aux k=1: G[1]; k=2: G[2..3]; k=3: G[4..7]; k=4..7: Qb[0..3] (+T)
    for (int k = 1; k < CL; ++k) {
        GemmDesc d = D0();
        d.a0 = Smir; d.a0_base = (long)(k - 1) * 512;
        d.a0_icl = 7; d.a0_is = COS; d.a0_os = TOS;
        d.b = G;  // F
        d.c_base = (long)k * 512;
        d.c_icl = 7; d.c_is = COS; d.c_os = TOS;
        d.beta = 2; d.cmbeta = Smir; d.cmb_base = (long)k * 512;
        d.cm = Smir; d.cm_base = (long)k * 512;
        d.gz_main = 1;
        int n;
        if (k == 1)      { d.xa = G;           d.xb = Gt;           d.xcm = G + MS;      d.xcmT = Gt + MS;      n = 1; }
        else if (k == 2) { d.xa = G;           d.xb = Gt + MS;      d.xcm = G + 2 * MS;  d.xcmT = Gt + 2 * MS;  n = 2; }
        else if (k == 3) { d.xa = G;           d.xb = Gt + 3 * MS;  d.xcm = G + 4 * MS;  d.xcmT = Gt + 4 * MS;  n = 4; }
        else if (k == 4) { d.xa = G + 7 * MS;  d.xb = Gt + 7 * MS;  d.xcm = Qb;          d.xcmT = Qtb;          n = 1; }
        else             { int j = k - 5;
                           d.xa = Qb + j * MS; d.xb = Qtb + j * MS; d.xcm = Qb + (j+1)*MS; d.xcmT = Qtb + (j+1)*MS; n = 1; }
        L(d, 4, 2, 64, 6, 1 + n);
    }

    // 4) initial carries a[c]
    init_carry_k<<<dim3(2048), dim3(256), 0, stream>>>(st0, Smir, a0m);

    // 5) Kogge-Stone (bf16 carries): nxt[r] = cur[r] + (r>=s*64 ? cur[r-s*64]@(F^{8s})^T : 0)
    //    aux s=1: Qb[4]=F^256 (+T); s=2: Qb[5]=F^512
    unsigned short* curm = a0m;
    unsigned short* nxtm = a1m;
    for (int s = 1; s < NC; s <<= 1) {
        GemmDesc d = D0();
        d.a0 = curm; d.a0_os = 512;
        d.a_shift = (long)s * 64;
        if (s == 1) { d.b = G + 7 * MS; }
        else        { d.b = Qb + (long)(__builtin_ctz(s) - 1) * MS; }
        d.beta = 2; d.cmbeta = curm; d.cmb_base = 0;
        d.cm = nxtm; d.c_os = 512;
        int n = 0;
        if (s == 1) { d.gz_main = 1; d.xa = Qb + 3 * MS; d.xb = Qtb + 3 * MS;
                      d.xcm = Qb + 4 * MS; d.xcmT = Qtb + 4 * MS; n = 1; }
        if (s == 2) { d.gz_main = 1; d.xa = Qb + 4 * MS; d.xb = Qtb + 4 * MS;
                      d.xcm = Qb + 5 * MS; d.xcmT = nullptr; n = 1; }
        L(d, 4, 2, 64, 6, 1 + n);
        unsigned short* tm = curm; curm = nxtm; nxtm = tm;
    }
    // after 7 rounds: curm = a1m

    // 6) fused phase3 + obs
    p3obs_k<<<dim3(1, 64, 8), dim3(512), 0, stream>>>(
        curm, G, Smir, BopO, Vn, states, obs);
}